// Round 15
// baseline (2624.658 us; speedup 1.0000x reference)
//
#include <hip/hip_runtime.h>
#include <hip/hip_bf16.h>
#include <stdint.h>

#define T_STEPS 16
#define T_CHUNK 4
#define NCHUNK  4
#define NN      20000
#define M_PAD   20032     // 626 * 32
#define NB32    626
#define NBC     5000      // conv blocks per slice (4 nodes each)
#define EE      640000
#define FF      64
#define HH      128
#define CC      16
#define BN_EPS  1e-5f
#define INVN    (1.0f/(float)NN)

typedef __hip_bfloat16 bf16;
typedef unsigned long long ull;
typedef __attribute__((ext_vector_type(8))) short short8;
typedef __attribute__((ext_vector_type(4))) float f32x4;

union V8 { short8 v; ushort u[8]; };

__device__ __forceinline__ float rdf(const void* p, long i, int isbf){
  return isbf ? __bfloat162float(((const bf16*)p)[i]) : ((const float*)p)[i];
}
__device__ __forceinline__ ushort f2bu(float f){
  bf16 h = __float2bfloat16(f);
  return *reinterpret_cast<ushort*>(&h);
}
__device__ __forceinline__ float bu2f(ushort u){
  return __uint_as_float((uint)u << 16);
}
__device__ __forceinline__ float blo(uint u){ return __uint_as_float(u << 16); }
__device__ __forceinline__ float bhi(uint u){ return __uint_as_float(u & 0xffff0000u); }

// ---------------- dtype probe (flag=1 iff buffers are bf16) ----------------
__global__ void k_detect(const void* x, int* flag){
  __shared__ int sh[256];
  int tid = threadIdx.x;
  const uint16_t* u = (const uint16_t*)x;
  uint16_t v = u[2*tid];
  int e = (v >> 7) & 0xFF;
  sh[tid] = (e >= 120 && e <= 134) ? 1 : 0;
  __syncthreads();
  for (int o = 128; o; o >>= 1){ if (tid < o) sh[tid] += sh[tid+o]; __syncthreads(); }
  if (tid == 0) flag[0] = (sh[0] >= 128) ? 1 : 0;
}

// ---------------- graph setup ----------------
// deg64: low 32 = Q20 fixed-point weighted degree (init 1<<20 = self-loop), high 32 = count
__global__ void k_init(ull* deg64, int* cursor, int n){
  int i = blockIdx.x*blockDim.x + threadIdx.x;
  if (i < n){ deg64[i] = (ull)(1u<<20); cursor[i] = 0; }
}
__global__ void k_deg(const int* dst, const void* w, ull* deg64, int e, const int* flag){
  int i = blockIdx.x*blockDim.x + threadIdx.x;
  if (i < e){
    float wv = rdf(w, i, *flag);
    ull pk = (1ULL<<32) | (ull)(uint)(wv*1048576.0f + 0.5f);
    atomicAdd(&deg64[dst[i]], pk);
  }
}
__global__ void k_dinv(const ull* deg64, float* dinv, float* selfnorm, int* cnt, int n){
  int i = blockIdx.x*blockDim.x + threadIdx.x;
  if (i < n){
    ull v = deg64[i];
    float d = (float)(uint)(v & 0xffffffffULL) * (1.0f/1048576.0f);
    cnt[i] = (int)(v >> 32);
    float r = d > 0.f ? rsqrtf(d) : 0.f;
    dinv[i] = r; selfnorm[i] = r*r;
  }
}
__global__ void k_scan(const int* cnt, int* offs, int n){
  __shared__ int part[256];
  int tid = threadIdx.x;
  int chunk = (n + 255)/256;
  int lo = tid*chunk; int hi = lo + chunk;
  if (hi > n) hi = n;
  if (lo > n) lo = n;
  int s = 0;
  for (int i = lo; i < hi; i++) s += cnt[i];
  part[tid] = s;
  __syncthreads();
  for (int off = 1; off < 256; off <<= 1){
    int t = (tid >= off) ? part[tid-off] : 0;
    __syncthreads();
    part[tid] += t;
    __syncthreads();
  }
  int run = part[tid] - s;
  for (int i = lo; i < hi; i++){ offs[i] = run; run += cnt[i]; }
  if (tid == 255) offs[n] = part[255];
}
__global__ void k_fill(const int* src, const int* dst, const void* w, const float* dinv,
                       const int* offs, int* cursor, int* csr_src, float* csr_norm, int e,
                       const int* flag){
  int i = blockIdx.x*blockDim.x + threadIdx.x;
  if (i < e){
    int s = src[i], d = dst[i];
    int pos = offs[d] + atomicAdd(&cursor[d], 1);
    csr_src[pos]  = s;
    csr_norm[pos] = dinv[s] * rdf(w, i, *flag) * dinv[d];
  }
}

__global__ void k_cvt(const void* src, long off, float* dst, int n, const int* flag){
  int i = blockIdx.x*blockDim.x + threadIdx.x;
  if (i < n) dst[i] = rdf(src, off + i, *flag);
}
__global__ void k_zero(float* p, int n){
  int i = blockIdx.x*blockDim.x + threadIdx.x;
  if (i < n) p[i] = 0.f;
}

// ---------------- weight swizzle into MFMA B-fragment order ----------------
// b-frag (ks, ct): lane l, elem j <- B[ks*32 + 8*(l>>4)+j][ct*16 + (l&15)]
// mode 0: B = src1 [K,N] row-major. mode 1: GRU cat K=256,N=512 from Wih/Whh [384,128].
__global__ void k_swz(const void* s1, const void* s2, ushort* dst,
                      int K, int N, int mode, const int* flag){
  int total = (K/32)*(N/16)*512;
  int o = blockIdx.x*blockDim.x + threadIdx.x;
  if (o >= total) return;
  int nct = N/16;
  int ks = o / (nct*512);
  int r1 = o % (nct*512);
  int ct = r1 / 512;
  int r2 = r1 % 512;
  int l  = r2 >> 3;
  int j  = r2 & 7;
  int k  = ks*32 + ((l>>4)<<3) + j;
  int c  = ct*16 + (l&15);
  float v;
  int isbf = *flag;
  if (mode == 0){
    v = rdf(s1, (long)k*N + c, isbf);
  } else {
    if (k < HH){
      if (c < 3*HH) v = rdf(s1, (long)c*HH + k, isbf);               // r,z,i_n from Wih
      else          v = 0.f;                                          // h_n x-part
    } else {
      int kh = k - HH;
      if (c < 2*HH)      v = rdf(s2, (long)c*HH + kh, isbf);         // r,z from Whh
      else if (c < 3*HH) v = 0.f;                                     // i_n h-part
      else               v = rdf(s2, (long)(c-HH)*HH + kh, isbf);    // h_n from Whh
    }
  }
  dst[o] = f2bu(v);
}

// bias4[c]: c<256: bih[c]+bhh[c]; c<384: bih[c]; else bhh[c-128]
__global__ void k_bias4(const void* bih, const void* bhh, float* bias4, const int* flag){
  int c = blockIdx.x*blockDim.x + threadIdx.x;
  if (c >= 4*HH) return;
  int isbf = *flag;
  float v;
  if (c < 2*HH)      v = rdf(bih, c, isbf) + rdf(bhh, c, isbf);
  else if (c < 3*HH) v = rdf(bih, c, isbf);
  else               v = rdf(bhh, c - HH, isbf);
  bias4[c] = v;
}

// ---------------- fused GCN input: h0 = relu(x@W_in+b); out = h0@W1 ----------------
// grid (NB32, T_CHUNK), 256 threads. out layout [slice][M_PAD][64], slice = tl*2+(col>=64)
__global__ __launch_bounds__(256) void k_gcn01(const void* xseq, int t0, const int* flag,
    const float* b_inF, const short8* B1, const short8* B2, ushort* out)
{
  __shared__ __align__(16) ushort As[32*64];
  __shared__ __align__(16) ushort Xs[32*128];
  const int tid = threadIdx.x;
  const int bm  = blockIdx.x*32;
  const int tl  = blockIdx.y;
  {
    int row = tid>>3, seg = tid&7;
    int grow = bm + row;
    int colu = seg*8;
    V8 r;
    if (grow < NN){
      long base = ((long)(t0+tl)*NN + grow)*FF + colu;
      if (*flag){
        r.v = *(const short8*)((const ushort*)xseq + base);
      } else {
        const f32x4* s = (const f32x4*)((const float*)xseq + base);
        f32x4 f0 = s[0], f1 = s[1];
        #pragma unroll
        for (int j=0;j<4;j++){ r.u[j]=f2bu(f0[j]); r.u[4+j]=f2bu(f1[j]); }
      }
    } else {
      #pragma unroll
      for (int j=0;j<8;j++) r.u[j] = 0;
    }
    *(short8*)&As[row*64 + (colu ^ ((row&7)<<3))] = r.v;
  }
  __syncthreads();
  const int w = tid>>6, l = tid&63;
  f32x4 acc[2][2];
  #pragma unroll
  for (int i=0;i<2;i++)
    #pragma unroll
    for (int j=0;j<2;j++) acc[i][j] = (f32x4){0.f,0.f,0.f,0.f};
  #pragma unroll
  for (int ks=0; ks<2; ks++){
    short8 a[2], b[2];
    #pragma unroll
    for (int rt=0;rt<2;rt++){
      int row = rt*16 + (l&15);
      int colu = ks*32 + ((l>>4)<<3);
      a[rt] = *reinterpret_cast<const short8*>(&As[row*64 + (colu ^ ((row&7)<<3))]);
    }
    #pragma unroll
    for (int c2=0;c2<2;c2++) b[c2] = B1[(ks*8 + w*2+c2)*64 + l];
    #pragma unroll
    for (int rt=0;rt<2;rt++)
      #pragma unroll
      for (int c2=0;c2<2;c2++)
        acc[rt][c2] = __builtin_amdgcn_mfma_f32_16x16x32_bf16(a[rt], b[c2], acc[rt][c2], 0,0,0);
  }
  // epilogue0 -> LDS (bias+relu)
  #pragma unroll
  for (int rt=0;rt<2;rt++)
    #pragma unroll
    for (int c2=0;c2<2;c2++){
      int col = w*32 + c2*16 + (l&15);
      #pragma unroll
      for (int reg=0;reg<4;reg++){
        int rl = rt*16 + ((l>>4)<<2) + reg;
        float v = fmaxf(acc[rt][c2][reg] + b_inF[col], 0.f);
        Xs[rl*128 + (col ^ ((rl&7)<<3))] = f2bu(v);
      }
    }
  __syncthreads();
  f32x4 acc1[2][2];
  #pragma unroll
  for (int i=0;i<2;i++)
    #pragma unroll
    for (int j=0;j<2;j++) acc1[i][j] = (f32x4){0.f,0.f,0.f,0.f};
  #pragma unroll
  for (int ks=0; ks<4; ks++){
    short8 a[2], b[2];
    #pragma unroll
    for (int rt=0;rt<2;rt++){
      int row = rt*16 + (l&15);
      int colu = ks*32 + ((l>>4)<<3);
      a[rt] = *reinterpret_cast<const short8*>(&Xs[row*128 + (colu ^ ((row&7)<<3))]);
    }
    #pragma unroll
    for (int c2=0;c2<2;c2++) b[c2] = B2[(ks*8 + w*2+c2)*64 + l];
    #pragma unroll
    for (int rt=0;rt<2;rt++)
      #pragma unroll
      for (int c2=0;c2<2;c2++)
        acc1[rt][c2] = __builtin_amdgcn_mfma_f32_16x16x32_bf16(a[rt], b[c2], acc1[rt][c2], 0,0,0);
  }
  #pragma unroll
  for (int rt=0;rt<2;rt++)
    #pragma unroll
    for (int c2=0;c2<2;c2++){
      int col = w*32 + c2*16 + (l&15);
      int slice = tl*2 + (col>>6);
      ushort* ob = out + (long)slice*M_PAD*64 + (col&63);
      #pragma unroll
      for (int reg=0;reg<4;reg++){
        int grow = bm + rt*16 + ((l>>4)<<2) + reg;
        __builtin_nontemporal_store(f2bu(acc1[rt][c2][reg]), ob + (long)grow*64);
      }
    }
}

// ---------------- batched GEMM2: out = (BN(A)+relu) @ W2, slice layout ----------------
__global__ __launch_bounds__(256) void k_mgemm2b(const ushort* Ain, const float* slots, int t0,
    const void* gw, const void* bew, const int* flag, const short8* B3, ushort* out)
{
  __shared__ __align__(16) ushort As[32*128];
  __shared__ float sc_s[HH], sh_s[HH];
  const int tid = threadIdx.x;
  const int bm  = blockIdx.x*32;
  const int tl  = blockIdx.y;
  const float* slot = slots + ((size_t)(t0+tl)*2 + 0)*2*HH;
  if (tid < HH){
    float mu  = slot[tid]*INVN;
    float var = fmaxf(slot[HH+tid]*INVN - mu*mu, 0.f);
    float sc  = rdf(gw, tid, *flag) * rsqrtf(var + BN_EPS);
    sc_s[tid] = sc;
    sh_s[tid] = rdf(bew, tid, *flag) - mu*sc;
  }
  __syncthreads();
  {
    int row = tid>>3, seg = tid&7;
    int grow = bm + row;
    #pragma unroll
    for (int i=0;i<2;i++){
      int colu = seg*16 + i*8;
      int slice = tl*2 + (colu>>6);
      V8 a; a.v = *(const short8*)(Ain + ((long)slice*M_PAD + grow)*64 + (colu&63));
      V8 r;
      #pragma unroll
      for (int j=0;j<8;j++){
        int k = colu + j;
        r.u[j] = f2bu(fmaxf(bu2f(a.u[j])*sc_s[k] + sh_s[k], 0.f));
      }
      *(short8*)&As[row*128 + (colu ^ ((row&7)<<3))] = r.v;
    }
  }
  __syncthreads();
  const int w = tid>>6, l = tid&63;
  f32x4 acc[2][2];
  #pragma unroll
  for (int i=0;i<2;i++)
    #pragma unroll
    for (int j=0;j<2;j++) acc[i][j] = (f32x4){0.f,0.f,0.f,0.f};
  #pragma unroll
  for (int ks=0; ks<4; ks++){
    short8 a[2], b[2];
    #pragma unroll
    for (int rt=0;rt<2;rt++){
      int row = rt*16 + (l&15);
      int colu = ks*32 + ((l>>4)<<3);
      a[rt] = *reinterpret_cast<const short8*>(&As[row*128 + (colu ^ ((row&7)<<3))]);
    }
    #pragma unroll
    for (int c2=0;c2<2;c2++) b[c2] = B3[(ks*8 + w*2+c2)*64 + l];
    #pragma unroll
    for (int rt=0;rt<2;rt++)
      #pragma unroll
      for (int c2=0;c2<2;c2++)
        acc[rt][c2] = __builtin_amdgcn_mfma_f32_16x16x32_bf16(a[rt], b[c2], acc[rt][c2], 0,0,0);
  }
  #pragma unroll
  for (int rt=0;rt<2;rt++)
    #pragma unroll
    for (int c2=0;c2<2;c2++){
      int col = w*32 + c2*16 + (l&15);
      int slice = tl*2 + (col>>6);
      ushort* ob = out + (long)slice*M_PAD*64 + (col&63);
      #pragma unroll
      for (int reg=0;reg<4;reg++){
        int grow = bm + rt*16 + ((l>>4)<<2) + reg;
        __builtin_nontemporal_store(f2bu(acc[rt][c2][reg]), ob + (long)grow*64);
      }
    }
}

// ---------------- fused double GRU step (per timestep; r12-proven shape) ----------------
// grid NB32, 512 threads (8 waves). 32 rows, full 128 h-cols, both layers; ping-pong h.
__global__ __launch_bounds__(512) void k_gru2(const ushort* agg, int tt, const float* slots, int t,
    const void* gw, const void* bew, const int* flag,
    const ushort* h0prev, const ushort* h1prev,
    const short8* BG0, const short8* BG1,
    const float* bias4_0, const float* bias4_1,
    ushort* h0out, ushort* h1out)
{
  __shared__ __align__(16) ushort As[32*256];
  __shared__ float sc_s[HH], sh_s[HH];
  const int tid = threadIdx.x;
  const int bm  = blockIdx.x*32;
  const float* slot = slots + ((size_t)t*2 + 1)*2*HH;
  if (tid < HH){
    float mu  = slot[tid]*INVN;
    float var = fmaxf(slot[HH+tid]*INVN - mu*mu, 0.f);
    float sc  = rdf(gw, tid, *flag) * rsqrtf(var + BN_EPS);
    sc_s[tid] = sc;
    sh_s[tid] = rdf(bew, tid, *flag) - mu*sc;
  }
  __syncthreads();
  // stage layer-0 A: cols 0-127 = BN(agg)+relu, cols 128-255 = h0prev (bf16 direct)
  {
    int row = tid>>4, seg = tid&15;
    int grow = bm + row;
    #pragma unroll
    for (int i=0;i<2;i++){
      int colu = seg*16 + i*8;
      V8 r;
      if (colu < 128){
        int slice = tt*2 + (colu>>6);
        V8 a; a.v = *(const short8*)(agg + ((long)slice*M_PAD + grow)*64 + (colu&63));
        #pragma unroll
        for (int j=0;j<8;j++){
          int k = colu + j;
          r.u[j] = f2bu(fmaxf(bu2f(a.u[j])*sc_s[k] + sh_s[k], 0.f));
        }
      } else {
        r.v = *(const short8*)(h0prev + (long)grow*HH + (colu-128));
      }
      *(short8*)&As[row*256 + (colu ^ ((row&7)<<3))] = r.v;
    }
  }
  __syncthreads();
  const int w = tid>>6, l = tid&63;   // 8 waves; wave w -> h-cols [w*16, w*16+16)
  const int col = w*16 + (l&15);
  f32x4 acc[2][4];
  #pragma unroll
  for (int i=0;i<2;i++)
    #pragma unroll
    for (int g=0;g<4;g++) acc[i][g] = (f32x4){0.f,0.f,0.f,0.f};
  #pragma unroll
  for (int ks=0; ks<8; ks++){
    short8 a[2];
    #pragma unroll
    for (int rt=0;rt<2;rt++){
      int row = rt*16 + (l&15);
      int colu = ks*32 + ((l>>4)<<3);
      a[rt] = *reinterpret_cast<const short8*>(&As[row*256 + (colu ^ ((row&7)<<3))]);
    }
    #pragma unroll
    for (int g=0;g<4;g++){
      short8 b = BG0[(ks*32 + g*8 + w)*64 + l];
      acc[0][g] = __builtin_amdgcn_mfma_f32_16x16x32_bf16(a[0], b, acc[0][g], 0,0,0);
      acc[1][g] = __builtin_amdgcn_mfma_f32_16x16x32_bf16(a[1], b, acc[1][g], 0,0,0);
    }
  }
  __syncthreads();
  // epilogue0: h0_new -> global (bf16) + LDS cols 0-127
  {
    float br = bias4_0[col], bz = bias4_0[HH+col], bi = bias4_0[2*HH+col], bh = bias4_0[3*HH+col];
    #pragma unroll
    for (int rt=0;rt<2;rt++)
      #pragma unroll
      for (int reg=0;reg<4;reg++){
        int rl = rt*16 + ((l>>4)<<2) + reg;
        int grow = bm + rl;
        float r = 1.f/(1.f + expf(-(acc[rt][0][reg] + br)));
        float z = 1.f/(1.f + expf(-(acc[rt][1][reg] + bz)));
        float nc = tanhf(acc[rt][2][reg] + bi + r*(acc[rt][3][reg] + bh));
        float hv = bu2f(h0prev[(long)grow*HH + col]);
        float hn = (1.f - z)*nc + z*hv;
        ushort hb = f2bu(hn);
        h0out[(long)grow*HH + col] = hb;
        As[rl*256 + (col ^ ((rl&7)<<3))] = hb;
      }
  }
  // stage h1prev into cols 128-255 (bf16 direct)
  {
    int row = tid>>4, seg = tid&15;
    if (seg >= 8){
      int grow = bm + row;
      #pragma unroll
      for (int i=0;i<2;i++){
        int colu = seg*16 + i*8;                      // 128..255
        V8 r; r.v = *(const short8*)(h1prev + (long)grow*HH + (colu-128));
        *(short8*)&As[row*256 + (colu ^ ((row&7)<<3))] = r.v;
      }
    }
  }
  __syncthreads();
  // layer 1
  f32x4 acc1[2][4];
  #pragma unroll
  for (int i=0;i<2;i++)
    #pragma unroll
    for (int g=0;g<4;g++) acc1[i][g] = (f32x4){0.f,0.f,0.f,0.f};
  #pragma unroll
  for (int ks=0; ks<8; ks++){
    short8 a[2];
    #pragma unroll
    for (int rt=0;rt<2;rt++){
      int row = rt*16 + (l&15);
      int colu = ks*32 + ((l>>4)<<3);
      a[rt] = *reinterpret_cast<const short8*>(&As[row*256 + (colu ^ ((row&7)<<3))]);
    }
    #pragma unroll
    for (int g=0;g<4;g++){
      short8 b = BG1[(ks*32 + g*8 + w)*64 + l];
      acc1[0][g] = __builtin_amdgcn_mfma_f32_16x16x32_bf16(a[0], b, acc1[0][g], 0,0,0);
      acc1[1][g] = __builtin_amdgcn_mfma_f32_16x16x32_bf16(a[1], b, acc1[1][g], 0,0,0);
    }
  }
  // epilogue1: h1_new -> global (bf16)
  {
    float br = bias4_1[col], bz = bias4_1[HH+col], bi = bias4_1[2*HH+col], bh = bias4_1[3*HH+col];
    #pragma unroll
    for (int rt=0;rt<2;rt++)
      #pragma unroll
      for (int reg=0;reg<4;reg++){
        int rl = rt*16 + ((l>>4)<<2) + reg;
        int grow = bm + rl;
        float r = 1.f/(1.f + expf(-(acc1[rt][0][reg] + br)));
        float z = 1.f/(1.f + expf(-(acc1[rt][1][reg] + bz)));
        float nc = tanhf(acc1[rt][2][reg] + bi + r*(acc1[rt][3][reg] + bh));
        float hv = bu2f(h1prev[(long)grow*HH + col]);
        h1out[(long)grow*HH + col] = f2bu((1.f - z)*nc + z*hv);
      }
  }
}

// ---------------- conv (CSR gather): slice-per-XCD, 4 edge-groups x dwordx2 ----------
// layout [slice][M_PAD][64], slice = blockIdx.x & 7 (XCD-pinned). One node per wave.
// Lane l: group g=l>>4 owns edges e0+g, e0+g+4, ...; 16 lanes/group cover 64 cols via
// uint2 (8B) gathers. No cndmask edge-select, no shfl in loop (~3 wave-VALU/edge vs
// r13's ~7+). Divergent group trip-counts are safe: shfl_xor reduce AFTER reconvergence.
__global__ __launch_bounds__(256) void k_conv(const ushort* __restrict__ in,
    ushort* __restrict__ out, const int* __restrict__ offs,
    const int* __restrict__ csr_src, const float* __restrict__ csr_norm,
    const float* __restrict__ selfn)
{
  const int slice = blockIdx.x & 7;
  const int n = (blockIdx.x >> 3)*4 + (threadIdx.x >> 6);
  const char* inB = (const char*)(in + (long)slice*M_PAD*64);
  const int l  = threadIdx.x & 63;
  const int g  = l >> 4;              // edge group 0..3
  const uint cb = (uint)(l & 15)*8u;  // byte offset in 128B row (4 bf16 cols)
  float a0 = 0.f, a1 = 0.f, a2 = 0.f, a3 = 0.f;
  if (g == 0){
    float sn = selfn[n];
    uint2 u = *(const uint2*)(inB + (((uint)n)<<7) + cb);
    a0 = sn*blo(u.x); a1 = sn*bhi(u.x);
    a2 = sn*blo(u.y); a3 = sn*bhi(u.y);
  }
  const int e0 = offs[n], e1 = offs[n+1];
  for (int e = e0 + g; e < e1; e += 4){
    int   s = __builtin_nontemporal_load(csr_src + e);
    float w = __builtin_nontemporal_load(csr_norm + e);
    uint2 u = *(const uint2*)(inB + (((uint)s)<<7) + cb);
    a0 += w*blo(u.x); a1 += w*bhi(u.x);
    a2 += w*blo(u.y); a3 += w*bhi(u.y);
  }
  a0 += __shfl_xor(a0, 16); a0 += __shfl_xor(a0, 32);
  a1 += __shfl_xor(a1, 16); a1 += __shfl_xor(a1, 32);
  a2 += __shfl_xor(a2, 16); a2 += __shfl_xor(a2, 32);
  a3 += __shfl_xor(a3, 16); a3 += __shfl_xor(a3, 32);
  if (g == 0){
    ull o = (ull)((uint)f2bu(a0) | ((uint)f2bu(a1) << 16))
          | ((ull)((uint)f2bu(a2) | ((uint)f2bu(a3) << 16)) << 32);
    __builtin_nontemporal_store(o,
        (ull*)((char*)(out + (long)slice*M_PAD*64) + (((uint)n)<<7) + cb));
  }
}

// ---------------- BN stats into slot (t0+tl, layer), slice layout ----------------
__global__ __launch_bounds__(256) void k_bnstats(const ushort* x, float* slots, int t0, int layer){
  const int tl = blockIdx.y;
  float* slot = slots + ((size_t)(t0+tl)*2 + layer)*2*HH;
  int h = threadIdx.x & 127;
  int g = threadIdx.x >> 7;
  int slice = tl*2 + (h>>6);
  const ushort* base = x + (long)slice*M_PAD*64 + (h&63);
  float s = 0.f, ss = 0.f;
  for (int r = blockIdx.x*2 + g; r < NN; r += gridDim.x*2){
    float v = bu2f(base[(long)r*64]);
    s += v; ss += v*v;
  }
  __shared__ float sh[2][HH], shq[2][HH];
  sh[g][h] = s; shq[g][h] = ss;
  __syncthreads();
  if (g == 0){
    atomicAdd(&slot[h],    sh[0][h] + sh[1][h]);
    atomicAdd(&slot[HH+h], shq[0][h] + shq[1][h]);
  }
}

// ---------------- output head (bf16 h input) ----------------
__global__ void k_out(const ushort* h, const float* Wo, const float* bo, void* out, int n,
                      const int* flag){
  __shared__ float Ws[HH][CC+1];
  __shared__ float bs[CC];
  int tid = threadIdx.x;
  for (int i = tid; i < HH*CC; i += 256) Ws[i/CC][i%CC] = Wo[i];
  if (tid < CC) bs[tid] = bo[tid];
  __syncthreads();
  int row = blockIdx.x*16 + (tid >> 4);
  int c   = tid & 15;
  if (row >= n) return;
  const ushort* hr = h + (size_t)row*HH;
  float s = bs[c];
  #pragma unroll 8
  for (int j = 0; j < HH; j++) s += bu2f(hr[j])*Ws[j][c];
  float m = s;
  for (int o = 8; o; o >>= 1) m = fmaxf(m, __shfl_xor(m, o, 16));
  float e = expf(s - m);
  float sum = e;
  for (int o = 8; o; o >>= 1) sum += __shfl_xor(sum, o, 16);
  float v = s - m - logf(sum);
  size_t idx = (size_t)row*CC + c;
  if (*flag) ((bf16*)out)[idx] = __float2bfloat16(v);
  else       ((float*)out)[idx] = v;
}

// ---------------- launcher ----------------
static inline size_t alignup(size_t x){ return (x + 255) & ~(size_t)255; }
static inline int ceil_div(int a, int b){ return (a + b - 1)/b; }

extern "C" void kernel_launch(void* const* d_in, const int* in_sizes, int n_in,
                              void* d_out, int out_size, void* d_ws, size_t ws_size,
                              hipStream_t stream){
  const void* x_seq = d_in[0];
  const int*  eidx  = (const int*)d_in[1];
  const void* ew    = d_in[2];
  const void* W_in  = d_in[3];
  const void* b_in  = d_in[4];
  const void* W1    = d_in[5];
  // d_in[6] = bc1 : cancels under training-mode BN
  const void* g1    = d_in[7];
  const void* be1   = d_in[8];
  const void* W2    = d_in[9];
  // d_in[10] = bc2 : cancels under BN
  const void* g2    = d_in[11];
  const void* be2   = d_in[12];
  const void* Wih0  = d_in[13];
  const void* Whh0  = d_in[14];
  const void* bih0  = d_in[15];
  const void* bhh0  = d_in[16];
  const void* Wih1  = d_in[17];
  const void* Whh1  = d_in[18];
  const void* bih1  = d_in[19];
  const void* bhh1  = d_in[20];
  const void* W_out = d_in[21];
  const void* b_out = d_in[22];
  const int* src = eidx;
  const int* dst = eidx + EE;

  // workspace (~90 MB)
  char* p = (char*)d_ws;
  auto alloc = [&](size_t bytes)->void*{ void* r = (void*)p; p += alignup(bytes); return r; };
  int*   flag     = (int*)  alloc(4);
  ull*   deg64    = (ull*)  alloc((size_t)NN*8);
  float* dinv     = (float*)alloc(NN*4);
  float* selfn    = (float*)alloc(NN*4);
  int*   cnt      = (int*)  alloc(NN*4);
  int*   cursor   = (int*)  alloc(NN*4);
  int*   offs     = (int*)  alloc((NN+1)*4);
  int*   csr_src  = (int*)  alloc((size_t)EE*4);
  float* csr_norm = (float*)alloc((size_t)EE*4);
  ushort* B1sw  = (ushort*)alloc((size_t)(FF/32)*(HH/16)*512*2);      // 16 KB
  ushort* B2sw  = (ushort*)alloc((size_t)(HH/32)*(HH/16)*512*2);      // 32 KB
  ushort* B3sw  = (ushort*)alloc((size_t)(HH/32)*(HH/16)*512*2);
  ushort* BG0sw = (ushort*)alloc((size_t)8*32*512*2);                 // 256 KB
  ushort* BG1sw = (ushort*)alloc((size_t)8*32*512*2);
  float* bias4_0 = (float*)alloc(4*HH*4);
  float* bias4_1 = (float*)alloc(4*HH*4);
  float* b_inF   = (float*)alloc(HH*4);
  float* W_outF  = (float*)alloc(HH*CC*4);
  float* b_outF  = (float*)alloc(CC*4);
  float* slots   = (float*)alloc((size_t)T_STEPS*2*2*HH*4);           // 64 KB
  ushort* temp2b = (ushort*)alloc((size_t)8*M_PAD*64*2);              // 20.5 MB [slice][M_PAD][64]
  ushort* agg1b  = (ushort*)alloc((size_t)8*M_PAD*64*2);
  ushort* agg2b  = (ushort*)alloc((size_t)8*M_PAD*64*2);
  ushort* h0bufA = (ushort*)alloc((size_t)M_PAD*HH*2);                // 5.13 MB (ping-pong, bf16)
  ushort* h0bufB = (ushort*)alloc((size_t)M_PAD*HH*2);
  ushort* h1bufA = (ushort*)alloc((size_t)M_PAD*HH*2);
  ushort* h1bufB = (ushort*)alloc((size_t)M_PAD*HH*2);
  (void)ws_size; (void)n_in; (void)in_sizes; (void)out_size;

  const int TPB = 256;
  // ---- dtype probe + graph setup ----
  k_detect<<<1, 256, 0, stream>>>(x_seq, flag);
  k_init<<<ceil_div(NN,TPB), TPB, 0, stream>>>(deg64, cursor, NN);
  k_deg <<<ceil_div(EE,TPB), TPB, 0, stream>>>(dst, ew, deg64, EE, flag);
  k_dinv<<<ceil_div(NN,TPB), TPB, 0, stream>>>(deg64, dinv, selfn, cnt, NN);
  k_scan<<<1, 256, 0, stream>>>(cnt, offs, NN);
  k_fill<<<ceil_div(EE,TPB), TPB, 0, stream>>>(src, dst, ew, dinv, offs, cursor, csr_src, csr_norm, EE, flag);

  // ---- weight prep ----
  k_swz<<<ceil_div(2*8*512,TPB), TPB, 0, stream>>>(W_in, nullptr, B1sw, FF, HH, 0, flag);
  k_swz<<<ceil_div(4*8*512,TPB), TPB, 0, stream>>>(W1,   nullptr, B2sw, HH, HH, 0, flag);
  k_swz<<<ceil_div(4*8*512,TPB), TPB, 0, stream>>>(W2,   nullptr, B3sw, HH, HH, 0, flag);
  k_swz<<<ceil_div(8*32*512,TPB), TPB, 0, stream>>>(Wih0, Whh0, BG0sw, 2*HH, 4*HH, 1, flag);
  k_swz<<<ceil_div(8*32*512,TPB), TPB, 0, stream>>>(Wih1, Whh1, BG1sw, 2*HH, 4*HH, 1, flag);
  k_bias4<<<2, 256, 0, stream>>>(bih0, bhh0, bias4_0, flag);
  k_bias4<<<2, 256, 0, stream>>>(bih1, bhh1, bias4_1, flag);
  k_cvt<<<1, 128, 0, stream>>>(b_in, 0, b_inF, HH, flag);
  k_cvt<<<ceil_div(HH*CC,TPB), TPB, 0, stream>>>(W_out, 0, W_outF, HH*CC, flag);
  k_cvt<<<1, CC, 0, stream>>>(b_out, 0, b_outF, CC, flag);
  int totHalf = M_PAD*HH/2;   // h buffers are bf16: zero as floats (0x0000 == bf16 0)
  k_zero<<<ceil_div(totHalf,TPB), TPB, 0, stream>>>((float*)h0bufA, totHalf);
  k_zero<<<ceil_div(totHalf,TPB), TPB, 0, stream>>>((float*)h1bufA, totHalf);
  k_zero<<<ceil_div(T_STEPS*2*2*HH,TPB), TPB, 0, stream>>>(slots, T_STEPS*2*2*HH);

  ushort* H0[2] = {h0bufA, h0bufB};
  ushort* H1[2] = {h1bufA, h1bufB};
  int cur = 0;

  // ---- main loop: 4 chunks of 4 timesteps ----
  for (int c = 0; c < NCHUNK; c++){
    int t0 = c*T_CHUNK;
    dim3 gg(NB32, T_CHUNK);
    dim3 gb(128, T_CHUNK);
    k_gcn01 <<<gg, 256, 0, stream>>>(x_seq, t0, flag, b_inF, (const short8*)B1sw, (const short8*)B2sw, temp2b);
    k_conv  <<<NBC*8, 256, 0, stream>>>(temp2b, agg1b, offs, csr_src, csr_norm, selfn);
    k_bnstats<<<gb, 256, 0, stream>>>(agg1b, slots, t0, 0);
    k_mgemm2b<<<gg, 256, 0, stream>>>(agg1b, slots, t0, g1, be1, flag, (const short8*)B3sw, temp2b);
    k_conv  <<<NBC*8, 256, 0, stream>>>(temp2b, agg2b, offs, csr_src, csr_norm, selfn);
    k_bnstats<<<gb, 256, 0, stream>>>(agg2b, slots, t0, 1);
    for (int tt = 0; tt < T_CHUNK; tt++){
      int t = t0 + tt;
      int nxt = cur ^ 1;
      k_gru2<<<NB32, 512, 0, stream>>>(agg2b, tt, slots, t,
                                       g2, be2, flag, H0[cur], H1[cur],
                                       (const short8*)BG0sw, (const short8*)BG1sw,
                                       bias4_0, bias4_1, H0[nxt], H1[nxt]);
      cur = nxt;
    }
  }

  // ---- output head ----
  k_out<<<ceil_div(NN,16), 256, 0, stream>>>(H1[cur], W_outF, b_outF, d_out, NN, flag);
}

// Round 16
// 1783.592 us; speedup vs baseline: 1.4716x; 1.4716x over previous
//
#include <hip/hip_runtime.h>
#include <hip/hip_bf16.h>
#include <stdint.h>

#define T_STEPS 16
#define T_CHUNK 4
#define NCHUNK  4
#define NN      20000
#define M_PAD   20032     // 626 * 32
#define NB32    626
#define NBC     5000      // conv blocks per slice (4 nodes each)
#define EE      640000
#define FF      64
#define HH      128
#define CC      16
#define BN_EPS  1e-5f
#define INVN    (1.0f/(float)NN)

typedef __hip_bfloat16 bf16;
typedef unsigned long long ull;
typedef __attribute__((ext_vector_type(8))) short short8;
typedef __attribute__((ext_vector_type(4))) float f32x4;

union V8 { short8 v; ushort u[8]; };

__device__ __forceinline__ float rdf(const void* p, long i, int isbf){
  return isbf ? __bfloat162float(((const bf16*)p)[i]) : ((const float*)p)[i];
}
__device__ __forceinline__ ushort f2bu(float f){
  bf16 h = __float2bfloat16(f);
  return *reinterpret_cast<ushort*>(&h);
}
__device__ __forceinline__ float bu2f(ushort u){
  return __uint_as_float((uint)u << 16);
}
__device__ __forceinline__ float blo(uint u){ return __uint_as_float(u << 16); }
__device__ __forceinline__ float bhi(uint u){ return __uint_as_float(u & 0xffff0000u); }

// ---------------- dtype probe (flag=1 iff buffers are bf16) ----------------
__global__ void k_detect(const void* x, int* flag){
  __shared__ int sh[256];
  int tid = threadIdx.x;
  const uint16_t* u = (const uint16_t*)x;
  uint16_t v = u[2*tid];
  int e = (v >> 7) & 0xFF;
  sh[tid] = (e >= 120 && e <= 134) ? 1 : 0;
  __syncthreads();
  for (int o = 128; o; o >>= 1){ if (tid < o) sh[tid] += sh[tid+o]; __syncthreads(); }
  if (tid == 0) flag[0] = (sh[0] >= 128) ? 1 : 0;
}

// ---------------- graph setup ----------------
// deg64: low 32 = Q20 fixed-point weighted degree (init 1<<20 = self-loop), high 32 = count
__global__ void k_init(ull* deg64, int* cursor, int n){
  int i = blockIdx.x*blockDim.x + threadIdx.x;
  if (i < n){ deg64[i] = (ull)(1u<<20); cursor[i] = 0; }
}
__global__ void k_deg(const int* dst, const void* w, ull* deg64, int e, const int* flag){
  int i = blockIdx.x*blockDim.x + threadIdx.x;
  if (i < e){
    float wv = rdf(w, i, *flag);
    ull pk = (1ULL<<32) | (ull)(uint)(wv*1048576.0f + 0.5f);
    atomicAdd(&deg64[dst[i]], pk);
  }
}
__global__ void k_dinv(const ull* deg64, float* dinv, float* selfnorm, int* cnt, int n){
  int i = blockIdx.x*blockDim.x + threadIdx.x;
  if (i < n){
    ull v = deg64[i];
    float d = (float)(uint)(v & 0xffffffffULL) * (1.0f/1048576.0f);
    cnt[i] = (int)(v >> 32);
    float r = d > 0.f ? rsqrtf(d) : 0.f;
    dinv[i] = r; selfnorm[i] = r*r;
  }
}
__global__ void k_scan(const int* cnt, int* offs, int n){
  __shared__ int part[256];
  int tid = threadIdx.x;
  int chunk = (n + 255)/256;
  int lo = tid*chunk; int hi = lo + chunk;
  if (hi > n) hi = n;
  if (lo > n) lo = n;
  int s = 0;
  for (int i = lo; i < hi; i++) s += cnt[i];
  part[tid] = s;
  __syncthreads();
  for (int off = 1; off < 256; off <<= 1){
    int t = (tid >= off) ? part[tid-off] : 0;
    __syncthreads();
    part[tid] += t;
    __syncthreads();
  }
  int run = part[tid] - s;
  for (int i = lo; i < hi; i++){ offs[i] = run; run += cnt[i]; }
  if (tid == 255) offs[n] = part[255];
}
// csr_boff stores src<<7 (byte offset of source row) -> gather addr is one v_add
__global__ void k_fill(const int* src, const int* dst, const void* w, const float* dinv,
                       const int* offs, int* cursor, int* csr_boff, float* csr_norm, int e,
                       const int* flag){
  int i = blockIdx.x*blockDim.x + threadIdx.x;
  if (i < e){
    int s = src[i], d = dst[i];
    int pos = offs[d] + atomicAdd(&cursor[d], 1);
    csr_boff[pos] = s << 7;
    csr_norm[pos] = dinv[s] * rdf(w, i, *flag) * dinv[d];
  }
}

__global__ void k_cvt(const void* src, long off, float* dst, int n, const int* flag){
  int i = blockIdx.x*blockDim.x + threadIdx.x;
  if (i < n) dst[i] = rdf(src, off + i, *flag);
}
__global__ void k_zero(float* p, int n){
  int i = blockIdx.x*blockDim.x + threadIdx.x;
  if (i < n) p[i] = 0.f;
}

// ---------------- weight swizzle into MFMA B-fragment order ----------------
// b-frag (ks, ct): lane l, elem j <- B[ks*32 + 8*(l>>4)+j][ct*16 + (l&15)]
// mode 0: B = src1 [K,N] row-major. mode 1: GRU cat K=256,N=512 from Wih/Whh [384,128].
__global__ void k_swz(const void* s1, const void* s2, ushort* dst,
                      int K, int N, int mode, const int* flag){
  int total = (K/32)*(N/16)*512;
  int o = blockIdx.x*blockDim.x + threadIdx.x;
  if (o >= total) return;
  int nct = N/16;
  int ks = o / (nct*512);
  int r1 = o % (nct*512);
  int ct = r1 / 512;
  int r2 = r1 % 512;
  int l  = r2 >> 3;
  int j  = r2 & 7;
  int k  = ks*32 + ((l>>4)<<3) + j;
  int c  = ct*16 + (l&15);
  float v;
  int isbf = *flag;
  if (mode == 0){
    v = rdf(s1, (long)k*N + c, isbf);
  } else {
    if (k < HH){
      if (c < 3*HH) v = rdf(s1, (long)c*HH + k, isbf);               // r,z,i_n from Wih
      else          v = 0.f;                                          // h_n x-part
    } else {
      int kh = k - HH;
      if (c < 2*HH)      v = rdf(s2, (long)c*HH + kh, isbf);         // r,z from Whh
      else if (c < 3*HH) v = 0.f;                                     // i_n h-part
      else               v = rdf(s2, (long)(c-HH)*HH + kh, isbf);    // h_n from Whh
    }
  }
  dst[o] = f2bu(v);
}

// bias4[c]: c<256: bih[c]+bhh[c]; c<384: bih[c]; else bhh[c-128]
__global__ void k_bias4(const void* bih, const void* bhh, float* bias4, const int* flag){
  int c = blockIdx.x*blockDim.x + threadIdx.x;
  if (c >= 4*HH) return;
  int isbf = *flag;
  float v;
  if (c < 2*HH)      v = rdf(bih, c, isbf) + rdf(bhh, c, isbf);
  else if (c < 3*HH) v = rdf(bih, c, isbf);
  else               v = rdf(bhh, c - HH, isbf);
  bias4[c] = v;
}

// ---------------- fused GCN input: h0 = relu(x@W_in+b); out = h0@W1 ----------------
// grid (NB32, T_CHUNK), 256 threads. out layout [slice][M_PAD][64], slice = tl*2+(col>=64)
__global__ __launch_bounds__(256) void k_gcn01(const void* xseq, int t0, const int* flag,
    const float* b_inF, const short8* B1, const short8* B2, ushort* out)
{
  __shared__ __align__(16) ushort As[32*64];
  __shared__ __align__(16) ushort Xs[32*128];
  const int tid = threadIdx.x;
  const int bm  = blockIdx.x*32;
  const int tl  = blockIdx.y;
  {
    int row = tid>>3, seg = tid&7;
    int grow = bm + row;
    int colu = seg*8;
    V8 r;
    if (grow < NN){
      long base = ((long)(t0+tl)*NN + grow)*FF + colu;
      if (*flag){
        r.v = *(const short8*)((const ushort*)xseq + base);
      } else {
        const f32x4* s = (const f32x4*)((const float*)xseq + base);
        f32x4 f0 = s[0], f1 = s[1];
        #pragma unroll
        for (int j=0;j<4;j++){ r.u[j]=f2bu(f0[j]); r.u[4+j]=f2bu(f1[j]); }
      }
    } else {
      #pragma unroll
      for (int j=0;j<8;j++) r.u[j] = 0;
    }
    *(short8*)&As[row*64 + (colu ^ ((row&7)<<3))] = r.v;
  }
  __syncthreads();
  const int w = tid>>6, l = tid&63;
  f32x4 acc[2][2];
  #pragma unroll
  for (int i=0;i<2;i++)
    #pragma unroll
    for (int j=0;j<2;j++) acc[i][j] = (f32x4){0.f,0.f,0.f,0.f};
  #pragma unroll
  for (int ks=0; ks<2; ks++){
    short8 a[2], b[2];
    #pragma unroll
    for (int rt=0;rt<2;rt++){
      int row = rt*16 + (l&15);
      int colu = ks*32 + ((l>>4)<<3);
      a[rt] = *reinterpret_cast<const short8*>(&As[row*64 + (colu ^ ((row&7)<<3))]);
    }
    #pragma unroll
    for (int c2=0;c2<2;c2++) b[c2] = B1[(ks*8 + w*2+c2)*64 + l];
    #pragma unroll
    for (int rt=0;rt<2;rt++)
      #pragma unroll
      for (int c2=0;c2<2;c2++)
        acc[rt][c2] = __builtin_amdgcn_mfma_f32_16x16x32_bf16(a[rt], b[c2], acc[rt][c2], 0,0,0);
  }
  // epilogue0 -> LDS (bias+relu)
  #pragma unroll
  for (int rt=0;rt<2;rt++)
    #pragma unroll
    for (int c2=0;c2<2;c2++){
      int col = w*32 + c2*16 + (l&15);
      #pragma unroll
      for (int reg=0;reg<4;reg++){
        int rl = rt*16 + ((l>>4)<<2) + reg;
        float v = fmaxf(acc[rt][c2][reg] + b_inF[col], 0.f);
        Xs[rl*128 + (col ^ ((rl&7)<<3))] = f2bu(v);
      }
    }
  __syncthreads();
  f32x4 acc1[2][2];
  #pragma unroll
  for (int i=0;i<2;i++)
    #pragma unroll
    for (int j=0;j<2;j++) acc1[i][j] = (f32x4){0.f,0.f,0.f,0.f};
  #pragma unroll
  for (int ks=0; ks<4; ks++){
    short8 a[2], b[2];
    #pragma unroll
    for (int rt=0;rt<2;rt++){
      int row = rt*16 + (l&15);
      int colu = ks*32 + ((l>>4)<<3);
      a[rt] = *reinterpret_cast<const short8*>(&Xs[row*128 + (colu ^ ((row&7)<<3))]);
    }
    #pragma unroll
    for (int c2=0;c2<2;c2++) b[c2] = B2[(ks*8 + w*2+c2)*64 + l];
    #pragma unroll
    for (int rt=0;rt<2;rt++)
      #pragma unroll
      for (int c2=0;c2<2;c2++)
        acc1[rt][c2] = __builtin_amdgcn_mfma_f32_16x16x32_bf16(a[rt], b[c2], acc1[rt][c2], 0,0,0);
  }
  #pragma unroll
  for (int rt=0;rt<2;rt++)
    #pragma unroll
    for (int c2=0;c2<2;c2++){
      int col = w*32 + c2*16 + (l&15);
      int slice = tl*2 + (col>>6);
      ushort* ob = out + (long)slice*M_PAD*64 + (col&63);
      #pragma unroll
      for (int reg=0;reg<4;reg++){
        int grow = bm + rt*16 + ((l>>4)<<2) + reg;
        __builtin_nontemporal_store(f2bu(acc1[rt][c2][reg]), ob + (long)grow*64);
      }
    }
}

// ---------------- batched GEMM2: out = (BN(A)+relu) @ W2, slice layout ----------------
__global__ __launch_bounds__(256) void k_mgemm2b(const ushort* Ain, const float* slots, int t0,
    const void* gw, const void* bew, const int* flag, const short8* B3, ushort* out)
{
  __shared__ __align__(16) ushort As[32*128];
  __shared__ float sc_s[HH], sh_s[HH];
  const int tid = threadIdx.x;
  const int bm  = blockIdx.x*32;
  const int tl  = blockIdx.y;
  const float* slot = slots + ((size_t)(t0+tl)*2 + 0)*2*HH;
  if (tid < HH){
    float mu  = slot[tid]*INVN;
    float var = fmaxf(slot[HH+tid]*INVN - mu*mu, 0.f);
    float sc  = rdf(gw, tid, *flag) * rsqrtf(var + BN_EPS);
    sc_s[tid] = sc;
    sh_s[tid] = rdf(bew, tid, *flag) - mu*sc;
  }
  __syncthreads();
  {
    int row = tid>>3, seg = tid&7;
    int grow = bm + row;
    #pragma unroll
    for (int i=0;i<2;i++){
      int colu = seg*16 + i*8;
      int slice = tl*2 + (colu>>6);
      V8 a; a.v = *(const short8*)(Ain + ((long)slice*M_PAD + grow)*64 + (colu&63));
      V8 r;
      #pragma unroll
      for (int j=0;j<8;j++){
        int k = colu + j;
        r.u[j] = f2bu(fmaxf(bu2f(a.u[j])*sc_s[k] + sh_s[k], 0.f));
      }
      *(short8*)&As[row*128 + (colu ^ ((row&7)<<3))] = r.v;
    }
  }
  __syncthreads();
  const int w = tid>>6, l = tid&63;
  f32x4 acc[2][2];
  #pragma unroll
  for (int i=0;i<2;i++)
    #pragma unroll
    for (int j=0;j<2;j++) acc[i][j] = (f32x4){0.f,0.f,0.f,0.f};
  #pragma unroll
  for (int ks=0; ks<4; ks++){
    short8 a[2], b[2];
    #pragma unroll
    for (int rt=0;rt<2;rt++){
      int row = rt*16 + (l&15);
      int colu = ks*32 + ((l>>4)<<3);
      a[rt] = *reinterpret_cast<const short8*>(&As[row*128 + (colu ^ ((row&7)<<3))]);
    }
    #pragma unroll
    for (int c2=0;c2<2;c2++) b[c2] = B3[(ks*8 + w*2+c2)*64 + l];
    #pragma unroll
    for (int rt=0;rt<2;rt++)
      #pragma unroll
      for (int c2=0;c2<2;c2++)
        acc[rt][c2] = __builtin_amdgcn_mfma_f32_16x16x32_bf16(a[rt], b[c2], acc[rt][c2], 0,0,0);
  }
  #pragma unroll
  for (int rt=0;rt<2;rt++)
    #pragma unroll
    for (int c2=0;c2<2;c2++){
      int col = w*32 + c2*16 + (l&15);
      int slice = tl*2 + (col>>6);
      ushort* ob = out + (long)slice*M_PAD*64 + (col&63);
      #pragma unroll
      for (int reg=0;reg<4;reg++){
        int grow = bm + rt*16 + ((l>>4)<<2) + reg;
        __builtin_nontemporal_store(f2bu(acc[rt][c2][reg]), ob + (long)grow*64);
      }
    }
}

// ---------------- fused double GRU step (per timestep; r12-proven shape) ----------------
// grid NB32, 512 threads (8 waves). 32 rows, full 128 h-cols, both layers; ping-pong h.
__global__ __launch_bounds__(512) void k_gru2(const ushort* agg, int tt, const float* slots, int t,
    const void* gw, const void* bew, const int* flag,
    const ushort* h0prev, const ushort* h1prev,
    const short8* BG0, const short8* BG1,
    const float* bias4_0, const float* bias4_1,
    ushort* h0out, ushort* h1out)
{
  __shared__ __align__(16) ushort As[32*256];
  __shared__ float sc_s[HH], sh_s[HH];
  const int tid = threadIdx.x;
  const int bm  = blockIdx.x*32;
  const float* slot = slots + ((size_t)t*2 + 1)*2*HH;
  if (tid < HH){
    float mu  = slot[tid]*INVN;
    float var = fmaxf(slot[HH+tid]*INVN - mu*mu, 0.f);
    float sc  = rdf(gw, tid, *flag) * rsqrtf(var + BN_EPS);
    sc_s[tid] = sc;
    sh_s[tid] = rdf(bew, tid, *flag) - mu*sc;
  }
  __syncthreads();
  // stage layer-0 A: cols 0-127 = BN(agg)+relu, cols 128-255 = h0prev (bf16 direct)
  {
    int row = tid>>4, seg = tid&15;
    int grow = bm + row;
    #pragma unroll
    for (int i=0;i<2;i++){
      int colu = seg*16 + i*8;
      V8 r;
      if (colu < 128){
        int slice = tt*2 + (colu>>6);
        V8 a; a.v = *(const short8*)(agg + ((long)slice*M_PAD + grow)*64 + (colu&63));
        #pragma unroll
        for (int j=0;j<8;j++){
          int k = colu + j;
          r.u[j] = f2bu(fmaxf(bu2f(a.u[j])*sc_s[k] + sh_s[k], 0.f));
        }
      } else {
        r.v = *(const short8*)(h0prev + (long)grow*HH + (colu-128));
      }
      *(short8*)&As[row*256 + (colu ^ ((row&7)<<3))] = r.v;
    }
  }
  __syncthreads();
  const int w = tid>>6, l = tid&63;   // 8 waves; wave w -> h-cols [w*16, w*16+16)
  const int col = w*16 + (l&15);
  f32x4 acc[2][4];
  #pragma unroll
  for (int i=0;i<2;i++)
    #pragma unroll
    for (int g=0;g<4;g++) acc[i][g] = (f32x4){0.f,0.f,0.f,0.f};
  #pragma unroll
  for (int ks=0; ks<8; ks++){
    short8 a[2];
    #pragma unroll
    for (int rt=0;rt<2;rt++){
      int row = rt*16 + (l&15);
      int colu = ks*32 + ((l>>4)<<3);
      a[rt] = *reinterpret_cast<const short8*>(&As[row*256 + (colu ^ ((row&7)<<3))]);
    }
    #pragma unroll
    for (int g=0;g<4;g++){
      short8 b = BG0[(ks*32 + g*8 + w)*64 + l];
      acc[0][g] = __builtin_amdgcn_mfma_f32_16x16x32_bf16(a[0], b, acc[0][g], 0,0,0);
      acc[1][g] = __builtin_amdgcn_mfma_f32_16x16x32_bf16(a[1], b, acc[1][g], 0,0,0);
    }
  }
  __syncthreads();
  // epilogue0: h0_new -> global (bf16) + LDS cols 0-127
  {
    float br = bias4_0[col], bz = bias4_0[HH+col], bi = bias4_0[2*HH+col], bh = bias4_0[3*HH+col];
    #pragma unroll
    for (int rt=0;rt<2;rt++)
      #pragma unroll
      for (int reg=0;reg<4;reg++){
        int rl = rt*16 + ((l>>4)<<2) + reg;
        int grow = bm + rl;
        float r = 1.f/(1.f + expf(-(acc[rt][0][reg] + br)));
        float z = 1.f/(1.f + expf(-(acc[rt][1][reg] + bz)));
        float nc = tanhf(acc[rt][2][reg] + bi + r*(acc[rt][3][reg] + bh));
        float hv = bu2f(h0prev[(long)grow*HH + col]);
        float hn = (1.f - z)*nc + z*hv;
        ushort hb = f2bu(hn);
        h0out[(long)grow*HH + col] = hb;
        As[rl*256 + (col ^ ((rl&7)<<3))] = hb;
      }
  }
  // stage h1prev into cols 128-255 (bf16 direct)
  {
    int row = tid>>4, seg = tid&15;
    if (seg >= 8){
      int grow = bm + row;
      #pragma unroll
      for (int i=0;i<2;i++){
        int colu = seg*16 + i*8;                      // 128..255
        V8 r; r.v = *(const short8*)(h1prev + (long)grow*HH + (colu-128));
        *(short8*)&As[row*256 + (colu ^ ((row&7)<<3))] = r.v;
      }
    }
  }
  __syncthreads();
  // layer 1
  f32x4 acc1[2][4];
  #pragma unroll
  for (int i=0;i<2;i++)
    #pragma unroll
    for (int g=0;g<4;g++) acc1[i][g] = (f32x4){0.f,0.f,0.f,0.f};
  #pragma unroll
  for (int ks=0; ks<8; ks++){
    short8 a[2];
    #pragma unroll
    for (int rt=0;rt<2;rt++){
      int row = rt*16 + (l&15);
      int colu = ks*32 + ((l>>4)<<3);
      a[rt] = *reinterpret_cast<const short8*>(&As[row*256 + (colu ^ ((row&7)<<3))]);
    }
    #pragma unroll
    for (int g=0;g<4;g++){
      short8 b = BG1[(ks*32 + g*8 + w)*64 + l];
      acc1[0][g] = __builtin_amdgcn_mfma_f32_16x16x32_bf16(a[0], b, acc1[0][g], 0,0,0);
      acc1[1][g] = __builtin_amdgcn_mfma_f32_16x16x32_bf16(a[1], b, acc1[1][g], 0,0,0);
    }
  }
  // epilogue1: h1_new -> global (bf16)
  {
    float br = bias4_1[col], bz = bias4_1[HH+col], bi = bias4_1[2*HH+col], bh = bias4_1[3*HH+col];
    #pragma unroll
    for (int rt=0;rt<2;rt++)
      #pragma unroll
      for (int reg=0;reg<4;reg++){
        int rl = rt*16 + ((l>>4)<<2) + reg;
        int grow = bm + rl;
        float r = 1.f/(1.f + expf(-(acc1[rt][0][reg] + br)));
        float z = 1.f/(1.f + expf(-(acc1[rt][1][reg] + bz)));
        float nc = tanhf(acc1[rt][2][reg] + bi + r*(acc1[rt][3][reg] + bh));
        float hv = bu2f(h1prev[(long)grow*HH + col]);
        h1out[(long)grow*HH + col] = f2bu((1.f - z)*nc + z*hv);
      }
  }
}

// ---------------- conv (CSR gather): r13 skeleton + uint2 gathers + pre-shifted boff --
// layout [slice][M_PAD][64], slice = blockIdx.x & 7 (XCD-pinned). One node per wave.
// e0/e1 wave-uniform (readfirstlane) -> metadata loads are uniform scalar loads OUTSIDE
// the gather chain (r13 lesson). 8-edge manual unroll; 4 groups of 16 lanes; group g
// takes edges e+g (low) and e+4+g (high) via loop-invariant cndmask selects; uint2 (8B)
// gathers -> 2 gathers/lane/iter (vs r13's 4). csr_boff pre-shifted (src<<7): 1 v_add/addr.
__global__ __launch_bounds__(256) void k_conv(const ushort* __restrict__ in,
    ushort* __restrict__ out, const int* __restrict__ offs,
    const int* __restrict__ csr_boff, const float* __restrict__ csr_norm,
    const float* __restrict__ selfn)
{
  const int slice = blockIdx.x & 7;
  const int n = (blockIdx.x >> 3)*4 + (threadIdx.x >> 6);
  const char* inB = (const char*)(in + (long)slice*M_PAD*64);
  const int l  = threadIdx.x & 63;
  const int g  = l >> 4;               // edge group 0..3
  const uint cb = (uint)(l & 15)*8u;   // byte offset in 128B row (4 bf16 cols)
  const bool g1b = (g & 1) != 0;
  const bool g2b = (g & 2) != 0;
  float a0 = 0.f, a1 = 0.f, a2 = 0.f, a3 = 0.f;
  if (g == 0){
    float sn = selfn[n];
    uint2 u = *(const uint2*)(inB + (((uint)n)<<7) + cb);
    a0 = sn*blo(u.x); a1 = sn*bhi(u.x);
    a2 = sn*blo(u.y); a3 = sn*bhi(u.y);
  }
  const int e0 = __builtin_amdgcn_readfirstlane(offs[n]);
  const int e1 = __builtin_amdgcn_readfirstlane(offs[n+1]);
  int e = e0;
  for (; e + 8 <= e1; e += 8){
    // uniform scalar loads (e wave-uniform) — stay OUT of the gather dependency chain
    int   b0 = csr_boff[e+0], b1 = csr_boff[e+1], b2 = csr_boff[e+2], b3 = csr_boff[e+3];
    int   b4 = csr_boff[e+4], b5 = csr_boff[e+5], b6 = csr_boff[e+6], b7 = csr_boff[e+7];
    float w0 = csr_norm[e+0], w1 = csr_norm[e+1], w2 = csr_norm[e+2], w3 = csr_norm[e+3];
    float w4 = csr_norm[e+4], w5 = csr_norm[e+5], w6 = csr_norm[e+6], w7 = csr_norm[e+7];
    int   ba = g2b ? (g1b ? b3 : b2) : (g1b ? b1 : b0);
    float wa = g2b ? (g1b ? w3 : w2) : (g1b ? w1 : w0);
    int   bb = g2b ? (g1b ? b7 : b6) : (g1b ? b5 : b4);
    float wb = g2b ? (g1b ? w7 : w6) : (g1b ? w5 : w4);
    uint2 ua = *(const uint2*)(inB + (uint)ba + cb);
    uint2 ub = *(const uint2*)(inB + (uint)bb + cb);
    a0 += wa*blo(ua.x) + wb*blo(ub.x);
    a1 += wa*bhi(ua.x) + wb*bhi(ub.x);
    a2 += wa*blo(ua.y) + wb*blo(ub.y);
    a3 += wa*bhi(ua.y) + wb*bhi(ub.y);
  }
  // remainder: <=2 guarded 4-edge passes (w=0 for out-of-range; b=0 stays in-bounds)
  for (; e < e1; e += 4){
    int idx = e + g;
    int bo = 0; float w = 0.f;
    if (idx < e1){ bo = csr_boff[idx]; w = csr_norm[idx]; }
    uint2 u = *(const uint2*)(inB + (uint)bo + cb);
    a0 += w*blo(u.x); a1 += w*bhi(u.x);
    a2 += w*blo(u.y); a3 += w*bhi(u.y);
  }
  a0 += __shfl_xor(a0, 16); a0 += __shfl_xor(a0, 32);
  a1 += __shfl_xor(a1, 16); a1 += __shfl_xor(a1, 32);
  a2 += __shfl_xor(a2, 16); a2 += __shfl_xor(a2, 32);
  a3 += __shfl_xor(a3, 16); a3 += __shfl_xor(a3, 32);
  if (g == 0){
    ull o = (ull)((uint)f2bu(a0) | ((uint)f2bu(a1) << 16))
          | ((ull)((uint)f2bu(a2) | ((uint)f2bu(a3) << 16)) << 32);
    __builtin_nontemporal_store(o,
        (ull*)((char*)(out + (long)slice*M_PAD*64) + (((uint)n)<<7) + cb));
  }
}

// ---------------- BN stats into slot (t0+tl, layer), slice layout ----------------
__global__ __launch_bounds__(256) void k_bnstats(const ushort* x, float* slots, int t0, int layer){
  const int tl = blockIdx.y;
  float* slot = slots + ((size_t)(t0+tl)*2 + layer)*2*HH;
  int h = threadIdx.x & 127;
  int g = threadIdx.x >> 7;
  int slice = tl*2 + (h>>6);
  const ushort* base = x + (long)slice*M_PAD*64 + (h&63);
  float s = 0.f, ss = 0.f;
  for (int r = blockIdx.x*2 + g; r < NN; r += gridDim.x*2){
    float v = bu2f(base[(long)r*64]);
    s += v; ss += v*v;
  }
  __shared__ float sh[2][HH], shq[2][HH];
  sh[g][h] = s; shq[g][h] = ss;
  __syncthreads();
  if (g == 0){
    atomicAdd(&slot[h],    sh[0][h] + sh[1][h]);
    atomicAdd(&slot[HH+h], shq[0][h] + shq[1][h]);
  }
}

// ---------------- output head (bf16 h input) ----------------
__global__ void k_out(const ushort* h, const float* Wo, const float* bo, void* out, int n,
                      const int* flag){
  __shared__ float Ws[HH][CC+1];
  __shared__ float bs[CC];
  int tid = threadIdx.x;
  for (int i = tid; i < HH*CC; i += 256) Ws[i/CC][i%CC] = Wo[i];
  if (tid < CC) bs[tid] = bo[tid];
  __syncthreads();
  int row = blockIdx.x*16 + (tid >> 4);
  int c   = tid & 15;
  if (row >= n) return;
  const ushort* hr = h + (size_t)row*HH;
  float s = bs[c];
  #pragma unroll 8
  for (int j = 0; j < HH; j++) s += bu2f(hr[j])*Ws[j][c];
  float m = s;
  for (int o = 8; o; o >>= 1) m = fmaxf(m, __shfl_xor(m, o, 16));
  float e = expf(s - m);
  float sum = e;
  for (int o = 8; o; o >>= 1) sum += __shfl_xor(sum, o, 16);
  float v = s - m - logf(sum);
  size_t idx = (size_t)row*CC + c;
  if (*flag) ((bf16*)out)[idx] = __float2bfloat16(v);
  else       ((float*)out)[idx] = v;
}

// ---------------- launcher ----------------
static inline size_t alignup(size_t x){ return (x + 255) & ~(size_t)255; }
static inline int ceil_div(int a, int b){ return (a + b - 1)/b; }

extern "C" void kernel_launch(void* const* d_in, const int* in_sizes, int n_in,
                              void* d_out, int out_size, void* d_ws, size_t ws_size,
                              hipStream_t stream){
  const void* x_seq = d_in[0];
  const int*  eidx  = (const int*)d_in[1];
  const void* ew    = d_in[2];
  const void* W_in  = d_in[3];
  const void* b_in  = d_in[4];
  const void* W1    = d_in[5];
  // d_in[6] = bc1 : cancels under training-mode BN
  const void* g1    = d_in[7];
  const void* be1   = d_in[8];
  const void* W2    = d_in[9];
  // d_in[10] = bc2 : cancels under BN
  const void* g2    = d_in[11];
  const void* be2   = d_in[12];
  const void* Wih0  = d_in[13];
  const void* Whh0  = d_in[14];
  const void* bih0  = d_in[15];
  const void* bhh0  = d_in[16];
  const void* Wih1  = d_in[17];
  const void* Whh1  = d_in[18];
  const void* bih1  = d_in[19];
  const void* bhh1  = d_in[20];
  const void* W_out = d_in[21];
  const void* b_out = d_in[22];
  const int* src = eidx;
  const int* dst = eidx + EE;

  // workspace (~90 MB)
  char* p = (char*)d_ws;
  auto alloc = [&](size_t bytes)->void*{ void* r = (void*)p; p += alignup(bytes); return r; };
  int*   flag     = (int*)  alloc(4);
  ull*   deg64    = (ull*)  alloc((size_t)NN*8);
  float* dinv     = (float*)alloc(NN*4);
  float* selfn    = (float*)alloc(NN*4);
  int*   cnt      = (int*)  alloc(NN*4);
  int*   cursor   = (int*)  alloc(NN*4);
  int*   offs     = (int*)  alloc((NN+1)*4);
  int*   csr_boff = (int*)  alloc((size_t)EE*4);
  float* csr_norm = (float*)alloc((size_t)EE*4);
  ushort* B1sw  = (ushort*)alloc((size_t)(FF/32)*(HH/16)*512*2);      // 16 KB
  ushort* B2sw  = (ushort*)alloc((size_t)(HH/32)*(HH/16)*512*2);      // 32 KB
  ushort* B3sw  = (ushort*)alloc((size_t)(HH/32)*(HH/16)*512*2);
  ushort* BG0sw = (ushort*)alloc((size_t)8*32*512*2);                 // 256 KB
  ushort* BG1sw = (ushort*)alloc((size_t)8*32*512*2);
  float* bias4_0 = (float*)alloc(4*HH*4);
  float* bias4_1 = (float*)alloc(4*HH*4);
  float* b_inF   = (float*)alloc(HH*4);
  float* W_outF  = (float*)alloc(HH*CC*4);
  float* b_outF  = (float*)alloc(CC*4);
  float* slots   = (float*)alloc((size_t)T_STEPS*2*2*HH*4);           // 64 KB
  ushort* temp2b = (ushort*)alloc((size_t)8*M_PAD*64*2);              // 20.5 MB [slice][M_PAD][64]
  ushort* agg1b  = (ushort*)alloc((size_t)8*M_PAD*64*2);
  ushort* agg2b  = (ushort*)alloc((size_t)8*M_PAD*64*2);
  ushort* h0bufA = (ushort*)alloc((size_t)M_PAD*HH*2);                // 5.13 MB (ping-pong, bf16)
  ushort* h0bufB = (ushort*)alloc((size_t)M_PAD*HH*2);
  ushort* h1bufA = (ushort*)alloc((size_t)M_PAD*HH*2);
  ushort* h1bufB = (ushort*)alloc((size_t)M_PAD*HH*2);
  (void)ws_size; (void)n_in; (void)in_sizes; (void)out_size;

  const int TPB = 256;
  // ---- dtype probe + graph setup ----
  k_detect<<<1, 256, 0, stream>>>(x_seq, flag);
  k_init<<<ceil_div(NN,TPB), TPB, 0, stream>>>(deg64, cursor, NN);
  k_deg <<<ceil_div(EE,TPB), TPB, 0, stream>>>(dst, ew, deg64, EE, flag);
  k_dinv<<<ceil_div(NN,TPB), TPB, 0, stream>>>(deg64, dinv, selfn, cnt, NN);
  k_scan<<<1, 256, 0, stream>>>(cnt, offs, NN);
  k_fill<<<ceil_div(EE,TPB), TPB, 0, stream>>>(src, dst, ew, dinv, offs, cursor, csr_boff, csr_norm, EE, flag);

  // ---- weight prep ----
  k_swz<<<ceil_div(2*8*512,TPB), TPB, 0, stream>>>(W_in, nullptr, B1sw, FF, HH, 0, flag);
  k_swz<<<ceil_div(4*8*512,TPB), TPB, 0, stream>>>(W1,   nullptr, B2sw, HH, HH, 0, flag);
  k_swz<<<ceil_div(4*8*512,TPB), TPB, 0, stream>>>(W2,   nullptr, B3sw, HH, HH, 0, flag);
  k_swz<<<ceil_div(8*32*512,TPB), TPB, 0, stream>>>(Wih0, Whh0, BG0sw, 2*HH, 4*HH, 1, flag);
  k_swz<<<ceil_div(8*32*512,TPB), TPB, 0, stream>>>(Wih1, Whh1, BG1sw, 2*HH, 4*HH, 1, flag);
  k_bias4<<<2, 256, 0, stream>>>(bih0, bhh0, bias4_0, flag);
  k_bias4<<<2, 256, 0, stream>>>(bih1, bhh1, bias4_1, flag);
  k_cvt<<<1, 128, 0, stream>>>(b_in, 0, b_inF, HH, flag);
  k_cvt<<<ceil_div(HH*CC,TPB), TPB, 0, stream>>>(W_out, 0, W_outF, HH*CC, flag);
  k_cvt<<<1, CC, 0, stream>>>(b_out, 0, b_outF, CC, flag);
  int totHalf = M_PAD*HH/2;   // h buffers are bf16: zero as floats (0x0000 == bf16 0)
  k_zero<<<ceil_div(totHalf,TPB), TPB, 0, stream>>>((float*)h0bufA, totHalf);
  k_zero<<<ceil_div(totHalf,TPB), TPB, 0, stream>>>((float*)h1bufA, totHalf);
  k_zero<<<ceil_div(T_STEPS*2*2*HH,TPB), TPB, 0, stream>>>(slots, T_STEPS*2*2*HH);

  ushort* H0[2] = {h0bufA, h0bufB};
  ushort* H1[2] = {h1bufA, h1bufB};
  int cur = 0;

  // ---- main loop: 4 chunks of 4 timesteps ----
  for (int c = 0; c < NCHUNK; c++){
    int t0 = c*T_CHUNK;
    dim3 gg(NB32, T_CHUNK);
    dim3 gb(128, T_CHUNK);
    k_gcn01 <<<gg, 256, 0, stream>>>(x_seq, t0, flag, b_inF, (const short8*)B1sw, (const short8*)B2sw, temp2b);
    k_conv  <<<NBC*8, 256, 0, stream>>>(temp2b, agg1b, offs, csr_boff, csr_norm, selfn);
    k_bnstats<<<gb, 256, 0, stream>>>(agg1b, slots, t0, 0);
    k_mgemm2b<<<gg, 256, 0, stream>>>(agg1b, slots, t0, g1, be1, flag, (const short8*)B3sw, temp2b);
    k_conv  <<<NBC*8, 256, 0, stream>>>(temp2b, agg2b, offs, csr_boff, csr_norm, selfn);
    k_bnstats<<<gb, 256, 0, stream>>>(agg2b, slots, t0, 1);
    for (int tt = 0; tt < T_CHUNK; tt++){
      int t = t0 + tt;
      int nxt = cur ^ 1;
      k_gru2<<<NB32, 512, 0, stream>>>(agg2b, tt, slots, t,
                                       g2, be2, flag, H0[cur], H1[cur],
                                       (const short8*)BG0sw, (const short8*)BG1sw,
                                       bias4_0, bias4_1, H0[nxt], H1[nxt]);
      cur = nxt;
    }
  }

  // ---- output head ----
  k_out<<<ceil_div(NN,16), 256, 0, stream>>>(H1[cur], W_outF, b_outF, d_out, NN, flag);
}

// Round 17
// 1663.191 us; speedup vs baseline: 1.5781x; 1.0724x over previous
//
#include <hip/hip_runtime.h>
#include <hip/hip_bf16.h>
#include <stdint.h>

#define T_STEPS 16
#define T_CHUNK 4
#define NCHUNK  4
#define NN      20000
#define M_PAD   20032     // 626 * 32
#define NB32    626
#define NBC     5000      // conv blocks per slice (4 nodes each)
#define EE      640000
#define FF      64
#define HH      128
#define CC      16
#define BN_EPS  1e-5f
#define INVN    (1.0f/(float)NN)

typedef __hip_bfloat16 bf16;
typedef unsigned long long ull;
typedef __attribute__((ext_vector_type(8))) short short8;
typedef __attribute__((ext_vector_type(4))) float f32x4;

union V8 { short8 v; ushort u[8]; };

__device__ __forceinline__ float rdf(const void* p, long i, int isbf){
  return isbf ? __bfloat162float(((const bf16*)p)[i]) : ((const float*)p)[i];
}
__device__ __forceinline__ ushort f2bu(float f){
  bf16 h = __float2bfloat16(f);
  return *reinterpret_cast<ushort*>(&h);
}
__device__ __forceinline__ float bu2f(ushort u){
  return __uint_as_float((uint)u << 16);
}
__device__ __forceinline__ float blo(uint u){ return __uint_as_float(u << 16); }
__device__ __forceinline__ float bhi(uint u){ return __uint_as_float(u & 0xffff0000u); }

// ---------------- init + dtype probe (block 0 probes; all blocks init) --------------
__global__ void k_init2(const void* x, int* flag, ull* deg64, int* cursor, int n){
  int i = blockIdx.x*blockDim.x + threadIdx.x;
  if (blockIdx.x == 0){
    __shared__ int sh[256];
    int tid = threadIdx.x;
    const uint16_t* u = (const uint16_t*)x;
    uint16_t v = u[2*tid];
    int e = (v >> 7) & 0xFF;
    sh[tid] = (e >= 120 && e <= 134) ? 1 : 0;
    __syncthreads();
    for (int o = 128; o; o >>= 1){ if (tid < o) sh[tid] += sh[tid+o]; __syncthreads(); }
    if (tid == 0) flag[0] = (sh[0] >= 128) ? 1 : 0;
  }
  if (i < n){ deg64[i] = (ull)(1u<<20); cursor[i] = 0; }
}

// ---------------- graph setup ----------------
__global__ void k_deg(const int* dst, const void* w, ull* deg64, int e, const int* flag){
  int i = blockIdx.x*blockDim.x + threadIdx.x;
  if (i < e){
    float wv = rdf(w, i, *flag);
    ull pk = (1ULL<<32) | (ull)(uint)(wv*1048576.0f + 0.5f);
    atomicAdd(&deg64[dst[i]], pk);
  }
}
__global__ void k_dinv(const ull* deg64, float* dinv, float* selfnorm, int* cnt, int n){
  int i = blockIdx.x*blockDim.x + threadIdx.x;
  if (i < n){
    ull v = deg64[i];
    float d = (float)(uint)(v & 0xffffffffULL) * (1.0f/1048576.0f);
    cnt[i] = (int)(v >> 32);
    float r = d > 0.f ? rsqrtf(d) : 0.f;
    dinv[i] = r; selfnorm[i] = r*r;
  }
}
__global__ void k_scan(const int* cnt, int* offs, int n){
  __shared__ int part[256];
  int tid = threadIdx.x;
  int chunk = (n + 255)/256;
  int lo = tid*chunk; int hi = lo + chunk;
  if (hi > n) hi = n;
  if (lo > n) lo = n;
  int s = 0;
  for (int i = lo; i < hi; i++) s += cnt[i];
  part[tid] = s;
  __syncthreads();
  for (int off = 1; off < 256; off <<= 1){
    int t = (tid >= off) ? part[tid-off] : 0;
    __syncthreads();
    part[tid] += t;
    __syncthreads();
  }
  int run = part[tid] - s;
  for (int i = lo; i < hi; i++){ offs[i] = run; run += cnt[i]; }
  if (tid == 255) offs[n] = part[255];
}
__global__ void k_fill(const int* src, const int* dst, const void* w, const float* dinv,
                       const int* offs, int* cursor, int* csr_src, float* csr_norm, int e,
                       const int* flag){
  int i = blockIdx.x*blockDim.x + threadIdx.x;
  if (i < e){
    int s = src[i], d = dst[i];
    int pos = offs[d] + atomicAdd(&cursor[d], 1);
    csr_src[pos]  = s;
    csr_norm[pos] = dinv[s] * rdf(w, i, *flag) * dinv[d];
  }
}

// ---------------- weight swizzle value (device fn) ----------------
// b-frag (ks, ct): lane l, elem j <- B[ks*32 + 8*(l>>4)+j][ct*16 + (l&15)]
// mode 0: B = s1 [K,N] row-major. mode 1: GRU cat K=256,N=512 from Wih/Whh [384,128].
__device__ float swz_val(const void* s1, const void* s2, int K, int N, int mode,
                         int o, int isbf){
  int nct = N/16;
  int ks = o / (nct*512);
  int r1 = o % (nct*512);
  int ct = r1 / 512;
  int r2 = r1 % 512;
  int l  = r2 >> 3;
  int j  = r2 & 7;
  int k  = ks*32 + ((l>>4)<<3) + j;
  int c  = ct*16 + (l&15);
  if (mode == 0) return rdf(s1, (long)k*N + c, isbf);
  if (k < HH){
    if (c < 3*HH) return rdf(s1, (long)c*HH + k, isbf);
    return 0.f;
  }
  int kh = k - HH;
  if (c < 2*HH)      return rdf(s2, (long)c*HH + kh, isbf);
  if (c < 3*HH)      return 0.f;
  return rdf(s2, (long)(c-HH)*HH + kh, isbf);
}
__device__ float bias4_val(const void* bih, const void* bhh, int c, int isbf){
  if (c < 2*HH) return rdf(bih, c, isbf) + rdf(bhh, c, isbf);
  if (c < 3*HH) return rdf(bih, c, isbf);
  return rdf(bhh, c - HH, isbf);
}

// ---------------- unified prep kernel (replaces 13 small launches) ----------------
#define P0 8192        // B1sw
#define P1 16384       // B2sw
#define P2 16384       // B3sw
#define P3 131072      // BG0sw
#define P4 131072      // BG1sw
#define P5 512         // bias4_0
#define P6 512         // bias4_1
#define P7 128         // b_inF
#define P8 2048        // W_outF
#define P9 16          // b_outF
#define P10 (M_PAD*HH/2)   // h0 zero (floats)
#define P11 (M_PAD*HH/2)   // h1 zero
#define P12 (T_STEPS*2*2*HH)  // slots zero
#define PREP_TOT (P0+P1+P2+P3+P4+P5+P6+P7+P8+P9+P10+P11+P12)
__global__ __launch_bounds__(256) void k_prep(
    const void* W_in, const void* W1, const void* W2,
    const void* Wih0, const void* Whh0, const void* Wih1, const void* Whh1,
    const void* bih0, const void* bhh0, const void* bih1, const void* bhh1,
    const void* b_in, const void* W_out, const void* b_out,
    ushort* B1sw, ushort* B2sw, ushort* B3sw, ushort* BG0sw, ushort* BG1sw,
    float* bias4_0, float* bias4_1, float* b_inF, float* W_outF, float* b_outF,
    float* h0z, float* h1z, float* slotz, const int* flag)
{
  long i = (long)blockIdx.x*256 + threadIdx.x;
  int isbf = *flag;
  if (i < P0){ B1sw[i] = f2bu(swz_val(W_in, nullptr, FF, HH, 0, (int)i, isbf)); return; }
  i -= P0;
  if (i < P1){ B2sw[i] = f2bu(swz_val(W1, nullptr, HH, HH, 0, (int)i, isbf)); return; }
  i -= P1;
  if (i < P2){ B3sw[i] = f2bu(swz_val(W2, nullptr, HH, HH, 0, (int)i, isbf)); return; }
  i -= P2;
  if (i < P3){ BG0sw[i] = f2bu(swz_val(Wih0, Whh0, 2*HH, 4*HH, 1, (int)i, isbf)); return; }
  i -= P3;
  if (i < P4){ BG1sw[i] = f2bu(swz_val(Wih1, Whh1, 2*HH, 4*HH, 1, (int)i, isbf)); return; }
  i -= P4;
  if (i < P5){ bias4_0[i] = bias4_val(bih0, bhh0, (int)i, isbf); return; }
  i -= P5;
  if (i < P6){ bias4_1[i] = bias4_val(bih1, bhh1, (int)i, isbf); return; }
  i -= P6;
  if (i < P7){ b_inF[i] = rdf(b_in, i, isbf); return; }
  i -= P7;
  if (i < P8){ W_outF[i] = rdf(W_out, i, isbf); return; }
  i -= P8;
  if (i < P9){ b_outF[i] = rdf(b_out, i, isbf); return; }
  i -= P9;
  if (i < P10){ h0z[i] = 0.f; return; }
  i -= P10;
  if (i < P11){ h1z[i] = 0.f; return; }
  i -= P11;
  if (i < P12){ slotz[i] = 0.f; return; }
}

// ---------------- fused GCN input: h0 = relu(x@W_in+b); out = h0@W1 ----------------
// grid (NB32, T_CHUNK), 256 threads. out layout [slice][M_PAD][64], slice = tl*2+(col>=64)
__global__ __launch_bounds__(256) void k_gcn01(const void* xseq, int t0, const int* flag,
    const float* b_inF, const short8* B1, const short8* B2, ushort* out)
{
  __shared__ __align__(16) ushort As[32*64];
  __shared__ __align__(16) ushort Xs[32*128];
  const int tid = threadIdx.x;
  const int bm  = blockIdx.x*32;
  const int tl  = blockIdx.y;
  {
    int row = tid>>3, seg = tid&7;
    int grow = bm + row;
    int colu = seg*8;
    V8 r;
    if (grow < NN){
      long base = ((long)(t0+tl)*NN + grow)*FF + colu;
      if (*flag){
        r.v = *(const short8*)((const ushort*)xseq + base);
      } else {
        const f32x4* s = (const f32x4*)((const float*)xseq + base);
        f32x4 f0 = s[0], f1 = s[1];
        #pragma unroll
        for (int j=0;j<4;j++){ r.u[j]=f2bu(f0[j]); r.u[4+j]=f2bu(f1[j]); }
      }
    } else {
      #pragma unroll
      for (int j=0;j<8;j++) r.u[j] = 0;
    }
    *(short8*)&As[row*64 + (colu ^ ((row&7)<<3))] = r.v;
  }
  __syncthreads();
  const int w = tid>>6, l = tid&63;
  f32x4 acc[2][2];
  #pragma unroll
  for (int i=0;i<2;i++)
    #pragma unroll
    for (int j=0;j<2;j++) acc[i][j] = (f32x4){0.f,0.f,0.f,0.f};
  #pragma unroll
  for (int ks=0; ks<2; ks++){
    short8 a[2], b[2];
    #pragma unroll
    for (int rt=0;rt<2;rt++){
      int row = rt*16 + (l&15);
      int colu = ks*32 + ((l>>4)<<3);
      a[rt] = *reinterpret_cast<const short8*>(&As[row*64 + (colu ^ ((row&7)<<3))]);
    }
    #pragma unroll
    for (int c2=0;c2<2;c2++) b[c2] = B1[(ks*8 + w*2+c2)*64 + l];
    #pragma unroll
    for (int rt=0;rt<2;rt++)
      #pragma unroll
      for (int c2=0;c2<2;c2++)
        acc[rt][c2] = __builtin_amdgcn_mfma_f32_16x16x32_bf16(a[rt], b[c2], acc[rt][c2], 0,0,0);
  }
  // epilogue0 -> LDS (bias+relu)
  #pragma unroll
  for (int rt=0;rt<2;rt++)
    #pragma unroll
    for (int c2=0;c2<2;c2++){
      int col = w*32 + c2*16 + (l&15);
      #pragma unroll
      for (int reg=0;reg<4;reg++){
        int rl = rt*16 + ((l>>4)<<2) + reg;
        float v = fmaxf(acc[rt][c2][reg] + b_inF[col], 0.f);
        Xs[rl*128 + (col ^ ((rl&7)<<3))] = f2bu(v);
      }
    }
  __syncthreads();
  f32x4 acc1[2][2];
  #pragma unroll
  for (int i=0;i<2;i++)
    #pragma unroll
    for (int j=0;j<2;j++) acc1[i][j] = (f32x4){0.f,0.f,0.f,0.f};
  #pragma unroll
  for (int ks=0; ks<4; ks++){
    short8 a[2], b[2];
    #pragma unroll
    for (int rt=0;rt<2;rt++){
      int row = rt*16 + (l&15);
      int colu = ks*32 + ((l>>4)<<3);
      a[rt] = *reinterpret_cast<const short8*>(&Xs[row*128 + (colu ^ ((row&7)<<3))]);
    }
    #pragma unroll
    for (int c2=0;c2<2;c2++) b[c2] = B2[(ks*8 + w*2+c2)*64 + l];
    #pragma unroll
    for (int rt=0;rt<2;rt++)
      #pragma unroll
      for (int c2=0;c2<2;c2++)
        acc1[rt][c2] = __builtin_amdgcn_mfma_f32_16x16x32_bf16(a[rt], b[c2], acc1[rt][c2], 0,0,0);
  }
  #pragma unroll
  for (int rt=0;rt<2;rt++)
    #pragma unroll
    for (int c2=0;c2<2;c2++){
      int col = w*32 + c2*16 + (l&15);
      int slice = tl*2 + (col>>6);
      ushort* ob = out + (long)slice*M_PAD*64 + (col&63);
      #pragma unroll
      for (int reg=0;reg<4;reg++){
        int grow = bm + rt*16 + ((l>>4)<<2) + reg;
        __builtin_nontemporal_store(f2bu(acc1[rt][c2][reg]), ob + (long)grow*64);
      }
    }
}

// ---------------- batched GEMM2: out = (BN(A)+relu) @ W2, slice layout ----------------
__global__ __launch_bounds__(256) void k_mgemm2b(const ushort* Ain, const float* slots, int t0,
    const void* gw, const void* bew, const int* flag, const short8* B3, ushort* out)
{
  __shared__ __align__(16) ushort As[32*128];
  __shared__ float sc_s[HH], sh_s[HH];
  const int tid = threadIdx.x;
  const int bm  = blockIdx.x*32;
  const int tl  = blockIdx.y;
  const float* slot = slots + ((size_t)(t0+tl)*2 + 0)*2*HH;
  if (tid < HH){
    float mu  = slot[tid]*INVN;
    float var = fmaxf(slot[HH+tid]*INVN - mu*mu, 0.f);
    float sc  = rdf(gw, tid, *flag) * rsqrtf(var + BN_EPS);
    sc_s[tid] = sc;
    sh_s[tid] = rdf(bew, tid, *flag) - mu*sc;
  }
  __syncthreads();
  {
    int row = tid>>3, seg = tid&7;
    int grow = bm + row;
    #pragma unroll
    for (int i=0;i<2;i++){
      int colu = seg*16 + i*8;
      int slice = tl*2 + (colu>>6);
      V8 a; a.v = *(const short8*)(Ain + ((long)slice*M_PAD + grow)*64 + (colu&63));
      V8 r;
      #pragma unroll
      for (int j=0;j<8;j++){
        int k = colu + j;
        r.u[j] = f2bu(fmaxf(bu2f(a.u[j])*sc_s[k] + sh_s[k], 0.f));
      }
      *(short8*)&As[row*128 + (colu ^ ((row&7)<<3))] = r.v;
    }
  }
  __syncthreads();
  const int w = tid>>6, l = tid&63;
  f32x4 acc[2][2];
  #pragma unroll
  for (int i=0;i<2;i++)
    #pragma unroll
    for (int j=0;j<2;j++) acc[i][j] = (f32x4){0.f,0.f,0.f,0.f};
  #pragma unroll
  for (int ks=0; ks<4; ks++){
    short8 a[2], b[2];
    #pragma unroll
    for (int rt=0;rt<2;rt++){
      int row = rt*16 + (l&15);
      int colu = ks*32 + ((l>>4)<<3);
      a[rt] = *reinterpret_cast<const short8*>(&As[row*128 + (colu ^ ((row&7)<<3))]);
    }
    #pragma unroll
    for (int c2=0;c2<2;c2++) b[c2] = B3[(ks*8 + w*2+c2)*64 + l];
    #pragma unroll
    for (int rt=0;rt<2;rt++)
      #pragma unroll
      for (int c2=0;c2<2;c2++)
        acc[rt][c2] = __builtin_amdgcn_mfma_f32_16x16x32_bf16(a[rt], b[c2], acc[rt][c2], 0,0,0);
  }
  #pragma unroll
  for (int rt=0;rt<2;rt++)
    #pragma unroll
    for (int c2=0;c2<2;c2++){
      int col = w*32 + c2*16 + (l&15);
      int slice = tl*2 + (col>>6);
      ushort* ob = out + (long)slice*M_PAD*64 + (col&63);
      #pragma unroll
      for (int reg=0;reg<4;reg++){
        int grow = bm + rt*16 + ((l>>4)<<2) + reg;
        __builtin_nontemporal_store(f2bu(acc[rt][c2][reg]), ob + (long)grow*64);
      }
    }
}

// ---------------- fused double GRU step (per timestep; r12-proven shape) ----------------
__global__ __launch_bounds__(512) void k_gru2(const ushort* agg, int tt, const float* slots, int t,
    const void* gw, const void* bew, const int* flag,
    const ushort* h0prev, const ushort* h1prev,
    const short8* BG0, const short8* BG1,
    const float* bias4_0, const float* bias4_1,
    ushort* h0out, ushort* h1out)
{
  __shared__ __align__(16) ushort As[32*256];
  __shared__ float sc_s[HH], sh_s[HH];
  const int tid = threadIdx.x;
  const int bm  = blockIdx.x*32;
  const float* slot = slots + ((size_t)t*2 + 1)*2*HH;
  if (tid < HH){
    float mu  = slot[tid]*INVN;
    float var = fmaxf(slot[HH+tid]*INVN - mu*mu, 0.f);
    float sc  = rdf(gw, tid, *flag) * rsqrtf(var + BN_EPS);
    sc_s[tid] = sc;
    sh_s[tid] = rdf(bew, tid, *flag) - mu*sc;
  }
  __syncthreads();
  {
    int row = tid>>4, seg = tid&15;
    int grow = bm + row;
    #pragma unroll
    for (int i=0;i<2;i++){
      int colu = seg*16 + i*8;
      V8 r;
      if (colu < 128){
        int slice = tt*2 + (colu>>6);
        V8 a; a.v = *(const short8*)(agg + ((long)slice*M_PAD + grow)*64 + (colu&63));
        #pragma unroll
        for (int j=0;j<8;j++){
          int k = colu + j;
          r.u[j] = f2bu(fmaxf(bu2f(a.u[j])*sc_s[k] + sh_s[k], 0.f));
        }
      } else {
        r.v = *(const short8*)(h0prev + (long)grow*HH + (colu-128));
      }
      *(short8*)&As[row*256 + (colu ^ ((row&7)<<3))] = r.v;
    }
  }
  __syncthreads();
  const int w = tid>>6, l = tid&63;
  const int col = w*16 + (l&15);
  f32x4 acc[2][4];
  #pragma unroll
  for (int i=0;i<2;i++)
    #pragma unroll
    for (int g=0;g<4;g++) acc[i][g] = (f32x4){0.f,0.f,0.f,0.f};
  #pragma unroll
  for (int ks=0; ks<8; ks++){
    short8 a[2];
    #pragma unroll
    for (int rt=0;rt<2;rt++){
      int row = rt*16 + (l&15);
      int colu = ks*32 + ((l>>4)<<3);
      a[rt] = *reinterpret_cast<const short8*>(&As[row*256 + (colu ^ ((row&7)<<3))]);
    }
    #pragma unroll
    for (int g=0;g<4;g++){
      short8 b = BG0[(ks*32 + g*8 + w)*64 + l];
      acc[0][g] = __builtin_amdgcn_mfma_f32_16x16x32_bf16(a[0], b, acc[0][g], 0,0,0);
      acc[1][g] = __builtin_amdgcn_mfma_f32_16x16x32_bf16(a[1], b, acc[1][g], 0,0,0);
    }
  }
  __syncthreads();
  {
    float br = bias4_0[col], bz = bias4_0[HH+col], bi = bias4_0[2*HH+col], bh = bias4_0[3*HH+col];
    #pragma unroll
    for (int rt=0;rt<2;rt++)
      #pragma unroll
      for (int reg=0;reg<4;reg++){
        int rl = rt*16 + ((l>>4)<<2) + reg;
        int grow = bm + rl;
        float r = 1.f/(1.f + expf(-(acc[rt][0][reg] + br)));
        float z = 1.f/(1.f + expf(-(acc[rt][1][reg] + bz)));
        float nc = tanhf(acc[rt][2][reg] + bi + r*(acc[rt][3][reg] + bh));
        float hv = bu2f(h0prev[(long)grow*HH + col]);
        float hn = (1.f - z)*nc + z*hv;
        ushort hb = f2bu(hn);
        h0out[(long)grow*HH + col] = hb;
        As[rl*256 + (col ^ ((rl&7)<<3))] = hb;
      }
  }
  {
    int row = tid>>4, seg = tid&15;
    if (seg >= 8){
      int grow = bm + row;
      #pragma unroll
      for (int i=0;i<2;i++){
        int colu = seg*16 + i*8;
        V8 r; r.v = *(const short8*)(h1prev + (long)grow*HH + (colu-128));
        *(short8*)&As[row*256 + (colu ^ ((row&7)<<3))] = r.v;
      }
    }
  }
  __syncthreads();
  f32x4 acc1[2][4];
  #pragma unroll
  for (int i=0;i<2;i++)
    #pragma unroll
    for (int g=0;g<4;g++) acc1[i][g] = (f32x4){0.f,0.f,0.f,0.f};
  #pragma unroll
  for (int ks=0; ks<8; ks++){
    short8 a[2];
    #pragma unroll
    for (int rt=0;rt<2;rt++){
      int row = rt*16 + (l&15);
      int colu = ks*32 + ((l>>4)<<3);
      a[rt] = *reinterpret_cast<const short8*>(&As[row*256 + (colu ^ ((row&7)<<3))]);
    }
    #pragma unroll
    for (int g=0;g<4;g++){
      short8 b = BG1[(ks*32 + g*8 + w)*64 + l];
      acc1[0][g] = __builtin_amdgcn_mfma_f32_16x16x32_bf16(a[0], b, acc1[0][g], 0,0,0);
      acc1[1][g] = __builtin_amdgcn_mfma_f32_16x16x32_bf16(a[1], b, acc1[1][g], 0,0,0);
    }
  }
  {
    float br = bias4_1[col], bz = bias4_1[HH+col], bi = bias4_1[2*HH+col], bh = bias4_1[3*HH+col];
    #pragma unroll
    for (int rt=0;rt<2;rt++)
      #pragma unroll
      for (int reg=0;reg<4;reg++){
        int rl = rt*16 + ((l>>4)<<2) + reg;
        int grow = bm + rl;
        float r = 1.f/(1.f + expf(-(acc1[rt][0][reg] + br)));
        float z = 1.f/(1.f + expf(-(acc1[rt][1][reg] + bz)));
        float nc = tanhf(acc1[rt][2][reg] + bi + r*(acc1[rt][3][reg] + bh));
        float hv = bu2f(h1prev[(long)grow*HH + col]);
        h1out[(long)grow*HH + col] = f2bu((1.f - z)*nc + z*hv);
      }
  }
}

// ---------------- conv (CSR gather): r14-exact (proven 86 us) ----------------
__global__ __launch_bounds__(256) void k_conv(const ushort* __restrict__ in,
    ushort* __restrict__ out, const int* __restrict__ offs,
    const int* __restrict__ csr_src, const float* __restrict__ csr_norm,
    const float* __restrict__ selfn)
{
  const int slice = blockIdx.x & 7;
  const int n = (blockIdx.x >> 3)*4 + (threadIdx.x >> 6);
  const char* inB = (const char*)(in + (long)slice*M_PAD*64);
  const int l    = threadIdx.x & 63;
  const int half = l >> 5;
  const uint laneoff = (uint)(l & 31)*4u;
  uint selfu = *(const uint*)(inB + (((uint)n)<<7) + laneoff);
  float ax = 0.f, ay = 0.f, ax2 = 0.f, ay2 = 0.f;
  if (half == 0){
    float sn = selfn[n];
    ax = sn*blo(selfu); ay = sn*bhi(selfu);
  }
  const int e0 = __builtin_amdgcn_readfirstlane(offs[n]);
  const int e1 = __builtin_amdgcn_readfirstlane(offs[n+1]);
  int e = e0;
  for (; e + 8 <= e1; e += 8){
    int   sA0 = csr_src[e+0], sB0 = csr_src[e+1];
    int   sA1 = csr_src[e+2], sB1 = csr_src[e+3];
    int   sA2 = csr_src[e+4], sB2 = csr_src[e+5];
    int   sA3 = csr_src[e+6], sB3 = csr_src[e+7];
    float wA0 = csr_norm[e+0], wB0 = csr_norm[e+1];
    float wA1 = csr_norm[e+2], wB1 = csr_norm[e+3];
    float wA2 = csr_norm[e+4], wB2 = csr_norm[e+5];
    float wA3 = csr_norm[e+6], wB3 = csr_norm[e+7];
    int   s0 = half ? sB0 : sA0;  float w0 = half ? wB0 : wA0;
    int   s1 = half ? sB1 : sA1;  float w1 = half ? wB1 : wA1;
    int   s2 = half ? sB2 : sA2;  float w2 = half ? wB2 : wA2;
    int   s3 = half ? sB3 : sA3;  float w3 = half ? wB3 : wA3;
    uint u0 = *(const uint*)(inB + (((uint)s0)<<7) + laneoff);
    uint u1 = *(const uint*)(inB + (((uint)s1)<<7) + laneoff);
    uint u2 = *(const uint*)(inB + (((uint)s2)<<7) + laneoff);
    uint u3 = *(const uint*)(inB + (((uint)s3)<<7) + laneoff);
    ax  += w0*blo(u0) + w1*blo(u1);
    ay  += w0*bhi(u0) + w1*bhi(u1);
    ax2 += w2*blo(u2) + w3*blo(u3);
    ay2 += w2*bhi(u2) + w3*bhi(u3);
  }
  for (; e < e1; e += 2){
    int sA = csr_src[e];  float wA = csr_norm[e];
    int sB = sA;          float wB = 0.f;
    if (e + 1 < e1){ sB = csr_src[e+1]; wB = csr_norm[e+1]; }
    int s = half ? sB : sA;  float w = half ? wB : wA;
    uint u = *(const uint*)(inB + (((uint)s)<<7) + laneoff);
    ax += w*blo(u); ay += w*bhi(u);
  }
  ax += ax2; ay += ay2;
  ax += __shfl_xor(ax, 32);
  ay += __shfl_xor(ay, 32);
  if (half == 0){
    uint o = (uint)f2bu(ax) | ((uint)f2bu(ay) << 16);
    __builtin_nontemporal_store(o, (uint*)(out + (long)slice*M_PAD*64 + (long)n*64 + (l&31)*2));
  }
}

// ---------------- BN stats into slot (t0+tl, layer), slice layout ----------------
__global__ __launch_bounds__(256) void k_bnstats(const ushort* x, float* slots, int t0, int layer){
  const int tl = blockIdx.y;
  float* slot = slots + ((size_t)(t0+tl)*2 + layer)*2*HH;
  int h = threadIdx.x & 127;
  int g = threadIdx.x >> 7;
  int slice = tl*2 + (h>>6);
  const ushort* base = x + (long)slice*M_PAD*64 + (h&63);
  float s = 0.f, ss = 0.f;
  for (int r = blockIdx.x*2 + g; r < NN; r += gridDim.x*2){
    float v = bu2f(base[(long)r*64]);
    s += v; ss += v*v;
  }
  __shared__ float sh[2][HH], shq[2][HH];
  sh[g][h] = s; shq[g][h] = ss;
  __syncthreads();
  if (g == 0){
    atomicAdd(&slot[h],    sh[0][h] + sh[1][h]);
    atomicAdd(&slot[HH+h], shq[0][h] + shq[1][h]);
  }
}

// ---------------- output head (bf16 h input) ----------------
__global__ void k_out(const ushort* h, const float* Wo, const float* bo, void* out, int n,
                      const int* flag){
  __shared__ float Ws[HH][CC+1];
  __shared__ float bs[CC];
  int tid = threadIdx.x;
  for (int i = tid; i < HH*CC; i += 256) Ws[i/CC][i%CC] = Wo[i];
  if (tid < CC) bs[tid] = bo[tid];
  __syncthreads();
  int row = blockIdx.x*16 + (tid >> 4);
  int c   = tid & 15;
  if (row >= n) return;
  const ushort* hr = h + (size_t)row*HH;
  float s = bs[c];
  #pragma unroll 8
  for (int j = 0; j < HH; j++) s += bu2f(hr[j])*Ws[j][c];
  float m = s;
  for (int o = 8; o; o >>= 1) m = fmaxf(m, __shfl_xor(m, o, 16));
  float e = expf(s - m);
  float sum = e;
  for (int o = 8; o; o >>= 1) sum += __shfl_xor(sum, o, 16);
  float v = s - m - logf(sum);
  size_t idx = (size_t)row*CC + c;
  if (*flag) ((bf16*)out)[idx] = __float2bfloat16(v);
  else       ((float*)out)[idx] = v;
}

// ---------------- launcher ----------------
static inline size_t alignup(size_t x){ return (x + 255) & ~(size_t)255; }
static inline int ceil_div(int a, int b){ return (a + b - 1)/b; }

extern "C" void kernel_launch(void* const* d_in, const int* in_sizes, int n_in,
                              void* d_out, int out_size, void* d_ws, size_t ws_size,
                              hipStream_t stream){
  const void* x_seq = d_in[0];
  const int*  eidx  = (const int*)d_in[1];
  const void* ew    = d_in[2];
  const void* W_in  = d_in[3];
  const void* b_in  = d_in[4];
  const void* W1    = d_in[5];
  // d_in[6] = bc1 : cancels under training-mode BN
  const void* g1    = d_in[7];
  const void* be1   = d_in[8];
  const void* W2    = d_in[9];
  // d_in[10] = bc2 : cancels under BN
  const void* g2    = d_in[11];
  const void* be2   = d_in[12];
  const void* Wih0  = d_in[13];
  const void* Whh0  = d_in[14];
  const void* bih0  = d_in[15];
  const void* bhh0  = d_in[16];
  const void* Wih1  = d_in[17];
  const void* Whh1  = d_in[18];
  const void* bih1  = d_in[19];
  const void* bhh1  = d_in[20];
  const void* W_out = d_in[21];
  const void* b_out = d_in[22];
  const int* src = eidx;
  const int* dst = eidx + EE;

  // workspace (~90 MB)
  char* p = (char*)d_ws;
  auto alloc = [&](size_t bytes)->void*{ void* r = (void*)p; p += alignup(bytes); return r; };
  int*   flag     = (int*)  alloc(4);
  ull*   deg64    = (ull*)  alloc((size_t)NN*8);
  float* dinv     = (float*)alloc(NN*4);
  float* selfn    = (float*)alloc(NN*4);
  int*   cnt      = (int*)  alloc(NN*4);
  int*   cursor   = (int*)  alloc(NN*4);
  int*   offs     = (int*)  alloc((NN+1)*4);
  int*   csr_src  = (int*)  alloc((size_t)EE*4);
  float* csr_norm = (float*)alloc((size_t)EE*4);
  ushort* B1sw  = (ushort*)alloc((size_t)P0*2);
  ushort* B2sw  = (ushort*)alloc((size_t)P1*2);
  ushort* B3sw  = (ushort*)alloc((size_t)P2*2);
  ushort* BG0sw = (ushort*)alloc((size_t)P3*2);
  ushort* BG1sw = (ushort*)alloc((size_t)P4*2);
  float* bias4_0 = (float*)alloc(4*HH*4);
  float* bias4_1 = (float*)alloc(4*HH*4);
  float* b_inF   = (float*)alloc(HH*4);
  float* W_outF  = (float*)alloc(HH*CC*4);
  float* b_outF  = (float*)alloc(CC*4);
  float* slots   = (float*)alloc((size_t)T_STEPS*2*2*HH*4);           // 64 KB
  ushort* temp2b = (ushort*)alloc((size_t)8*M_PAD*64*2);              // 20.5 MB [slice][M_PAD][64]
  ushort* agg1b  = (ushort*)alloc((size_t)8*M_PAD*64*2);
  ushort* agg2b  = (ushort*)alloc((size_t)8*M_PAD*64*2);
  ushort* h0bufA = (ushort*)alloc((size_t)M_PAD*HH*2);                // 5.13 MB (ping-pong, bf16)
  ushort* h0bufB = (ushort*)alloc((size_t)M_PAD*HH*2);
  ushort* h1bufA = (ushort*)alloc((size_t)M_PAD*HH*2);
  ushort* h1bufB = (ushort*)alloc((size_t)M_PAD*HH*2);
  (void)ws_size; (void)n_in; (void)in_sizes; (void)out_size;

  const int TPB = 256;
  // ---- init (+probe in block 0), graph setup ----
  k_init2<<<ceil_div(NN,TPB), TPB, 0, stream>>>(x_seq, flag, deg64, cursor, NN);
  k_prep<<<ceil_div(PREP_TOT,TPB), TPB, 0, stream>>>(
      W_in, W1, W2, Wih0, Whh0, Wih1, Whh1, bih0, bhh0, bih1, bhh1,
      b_in, W_out, b_out,
      B1sw, B2sw, B3sw, BG0sw, BG1sw,
      bias4_0, bias4_1, b_inF, W_outF, b_outF,
      (float*)h0bufA, (float*)h1bufA, slots, flag);
  k_deg <<<ceil_div(EE,TPB), TPB, 0, stream>>>(dst, ew, deg64, EE, flag);
  k_dinv<<<ceil_div(NN,TPB), TPB, 0, stream>>>(deg64, dinv, selfn, cnt, NN);
  k_scan<<<1, 256, 0, stream>>>(cnt, offs, NN);
  k_fill<<<ceil_div(EE,TPB), TPB, 0, stream>>>(src, dst, ew, dinv, offs, cursor, csr_src, csr_norm, EE, flag);

  ushort* H0[2] = {h0bufA, h0bufB};
  ushort* H1[2] = {h1bufA, h1bufB};
  int cur = 0;

  // ---- main loop: 4 chunks of 4 timesteps ----
  for (int c = 0; c < NCHUNK; c++){
    int t0 = c*T_CHUNK;
    dim3 gg(NB32, T_CHUNK);
    dim3 gb(128, T_CHUNK);
    k_gcn01 <<<gg, 256, 0, stream>>>(x_seq, t0, flag, b_inF, (const short8*)B1sw, (const short8*)B2sw, temp2b);
    k_conv  <<<NBC*8, 256, 0, stream>>>(temp2b, agg1b, offs, csr_src, csr_norm, selfn);
    k_bnstats<<<gb, 256, 0, stream>>>(agg1b, slots, t0, 0);
    k_mgemm2b<<<gg, 256, 0, stream>>>(agg1b, slots, t0, g1, be1, flag, (const short8*)B3sw, temp2b);
    k_conv  <<<NBC*8, 256, 0, stream>>>(temp2b, agg2b, offs, csr_src, csr_norm, selfn);
    k_bnstats<<<gb, 256, 0, stream>>>(agg2b, slots, t0, 1);
    for (int tt = 0; tt < T_CHUNK; tt++){
      int t = t0 + tt;
      int nxt = cur ^ 1;
      k_gru2<<<NB32, 512, 0, stream>>>(agg2b, tt, slots, t,
                                       g2, be2, flag, H0[cur], H1[cur],
                                       (const short8*)BG0sw, (const short8*)BG1sw,
                                       bias4_0, bias4_1, H0[nxt], H1[nxt]);
      cur = nxt;
    }
  }

  // ---- output head ----
  k_out<<<ceil_div(NN,16), 256, 0, stream>>>(H1[cur], W_outF, b_outF, d_out, NN, flag);
}

// Round 18
// 1460.715 us; speedup vs baseline: 1.7968x; 1.1386x over previous
//
#include <hip/hip_runtime.h>
#include <hip/hip_bf16.h>
#include <stdint.h>

#define T_STEPS 16
#define T_CHUNK 4
#define NCHUNK  4
#define NN      20000
#define M_PAD   20032     // 626 * 32
#define NB32    626
#define NBC     5000      // conv blocks per tl (4 nodes each)
#define EE      640000
#define FF      64
#define HH      128
#define CC      16
#define BN_EPS  1e-5f
#define INVN    (1.0f/(float)NN)
#define SLICE_E ((long)M_PAD*64)

typedef __hip_bfloat16 bf16;
typedef unsigned long long ull;
typedef __attribute__((ext_vector_type(8))) short short8;
typedef __attribute__((ext_vector_type(4))) float f32x4;

union V8 { short8 v; ushort u[8]; };

__device__ __forceinline__ float rdf(const void* p, long i, int isbf){
  return isbf ? __bfloat162float(((const bf16*)p)[i]) : ((const float*)p)[i];
}
__device__ __forceinline__ ushort f2bu(float f){
  bf16 h = __float2bfloat16(f);
  return *reinterpret_cast<ushort*>(&h);
}
__device__ __forceinline__ float bu2f(ushort u){
  return __uint_as_float((uint)u << 16);
}
__device__ __forceinline__ float blo(uint u){ return __uint_as_float(u << 16); }
__device__ __forceinline__ float bhi(uint u){ return __uint_as_float(u & 0xffff0000u); }

// ---------------- init + dtype probe (block 0 probes; all blocks init) --------------
__global__ void k_init2(const void* x, int* flag, ull* deg64, int* cursor, int n){
  int i = blockIdx.x*blockDim.x + threadIdx.x;
  if (blockIdx.x == 0){
    __shared__ int sh[256];
    int tid = threadIdx.x;
    const uint16_t* u = (const uint16_t*)x;
    uint16_t v = u[2*tid];
    int e = (v >> 7) & 0xFF;
    sh[tid] = (e >= 120 && e <= 134) ? 1 : 0;
    __syncthreads();
    for (int o = 128; o; o >>= 1){ if (tid < o) sh[tid] += sh[tid+o]; __syncthreads(); }
    if (tid == 0) flag[0] = (sh[0] >= 128) ? 1 : 0;
  }
  if (i < n){ deg64[i] = (ull)(1u<<20); cursor[i] = 0; }
}

// ---------------- graph setup ----------------
__global__ void k_deg(const int* dst, const void* w, ull* deg64, int e, const int* flag){
  int i = blockIdx.x*blockDim.x + threadIdx.x;
  if (i < e){
    float wv = rdf(w, i, *flag);
    ull pk = (1ULL<<32) | (ull)(uint)(wv*1048576.0f + 0.5f);
    atomicAdd(&deg64[dst[i]], pk);
  }
}
__global__ void k_dinv(const ull* deg64, float* dinv, float* selfnorm, int* cnt, int n){
  int i = blockIdx.x*blockDim.x + threadIdx.x;
  if (i < n){
    ull v = deg64[i];
    float d = (float)(uint)(v & 0xffffffffULL) * (1.0f/1048576.0f);
    cnt[i] = (int)(v >> 32);
    float r = d > 0.f ? rsqrtf(d) : 0.f;
    dinv[i] = r; selfnorm[i] = r*r;
  }
}
__global__ void k_scan(const int* cnt, int* offs, int n){
  __shared__ int part[256];
  int tid = threadIdx.x;
  int chunk = (n + 255)/256;
  int lo = tid*chunk; int hi = lo + chunk;
  if (hi > n) hi = n;
  if (lo > n) lo = n;
  int s = 0;
  for (int i = lo; i < hi; i++) s += cnt[i];
  part[tid] = s;
  __syncthreads();
  for (int off = 1; off < 256; off <<= 1){
    int t = (tid >= off) ? part[tid-off] : 0;
    __syncthreads();
    part[tid] += t;
    __syncthreads();
  }
  int run = part[tid] - s;
  for (int i = lo; i < hi; i++){ offs[i] = run; run += cnt[i]; }
  if (tid == 255) offs[n] = part[255];
}
__global__ void k_fill(const int* src, const int* dst, const void* w, const float* dinv,
                       const int* offs, int* cursor, int* csr_src, float* csr_norm, int e,
                       const int* flag){
  int i = blockIdx.x*blockDim.x + threadIdx.x;
  if (i < e){
    int s = src[i], d = dst[i];
    int pos = offs[d] + atomicAdd(&cursor[d], 1);
    csr_src[pos]  = s;
    csr_norm[pos] = dinv[s] * rdf(w, i, *flag) * dinv[d];
  }
}

// ---------------- weight swizzle value (device fn) ----------------
__device__ float swz_val(const void* s1, const void* s2, int K, int N, int mode,
                         int o, int isbf){
  int nct = N/16;
  int ks = o / (nct*512);
  int r1 = o % (nct*512);
  int ct = r1 / 512;
  int r2 = r1 % 512;
  int l  = r2 >> 3;
  int j  = r2 & 7;
  int k  = ks*32 + ((l>>4)<<3) + j;
  int c  = ct*16 + (l&15);
  if (mode == 0) return rdf(s1, (long)k*N + c, isbf);
  if (k < HH){
    if (c < 3*HH) return rdf(s1, (long)c*HH + k, isbf);
    return 0.f;
  }
  int kh = k - HH;
  if (c < 2*HH)      return rdf(s2, (long)c*HH + kh, isbf);
  if (c < 3*HH)      return 0.f;
  return rdf(s2, (long)(c-HH)*HH + kh, isbf);
}
__device__ float bias4_val(const void* bih, const void* bhh, int c, int isbf){
  if (c < 2*HH) return rdf(bih, c, isbf) + rdf(bhh, c, isbf);
  if (c < 3*HH) return rdf(bih, c, isbf);
  return rdf(bhh, c - HH, isbf);
}

// ---------------- unified prep kernel ----------------
#define P0 8192
#define P1 16384
#define P2 16384
#define P3 131072
#define P4 131072
#define P5 512
#define P6 512
#define P7 128
#define P8 2048
#define P9 16
#define P10 (M_PAD*HH/2)
#define P11 (M_PAD*HH/2)
#define P12 (T_STEPS*2*2*HH)
#define PREP_TOT (P0+P1+P2+P3+P4+P5+P6+P7+P8+P9+P10+P11+P12)
__global__ __launch_bounds__(256) void k_prep(
    const void* W_in, const void* W1, const void* W2,
    const void* Wih0, const void* Whh0, const void* Wih1, const void* Whh1,
    const void* bih0, const void* bhh0, const void* bih1, const void* bhh1,
    const void* b_in, const void* W_out, const void* b_out,
    ushort* B1sw, ushort* B2sw, ushort* B3sw, ushort* BG0sw, ushort* BG1sw,
    float* bias4_0, float* bias4_1, float* b_inF, float* W_outF, float* b_outF,
    float* h0z, float* h1z, float* slotz, const int* flag)
{
  long i = (long)blockIdx.x*256 + threadIdx.x;
  int isbf = *flag;
  if (i < P0){ B1sw[i] = f2bu(swz_val(W_in, nullptr, FF, HH, 0, (int)i, isbf)); return; }
  i -= P0;
  if (i < P1){ B2sw[i] = f2bu(swz_val(W1, nullptr, HH, HH, 0, (int)i, isbf)); return; }
  i -= P1;
  if (i < P2){ B3sw[i] = f2bu(swz_val(W2, nullptr, HH, HH, 0, (int)i, isbf)); return; }
  i -= P2;
  if (i < P3){ BG0sw[i] = f2bu(swz_val(Wih0, Whh0, 2*HH, 4*HH, 1, (int)i, isbf)); return; }
  i -= P3;
  if (i < P4){ BG1sw[i] = f2bu(swz_val(Wih1, Whh1, 2*HH, 4*HH, 1, (int)i, isbf)); return; }
  i -= P4;
  if (i < P5){ bias4_0[i] = bias4_val(bih0, bhh0, (int)i, isbf); return; }
  i -= P5;
  if (i < P6){ bias4_1[i] = bias4_val(bih1, bhh1, (int)i, isbf); return; }
  i -= P6;
  if (i < P7){ b_inF[i] = rdf(b_in, i, isbf); return; }
  i -= P7;
  if (i < P8){ W_outF[i] = rdf(W_out, i, isbf); return; }
  i -= P8;
  if (i < P9){ b_outF[i] = rdf(b_out, i, isbf); return; }
  i -= P9;
  if (i < P10){ h0z[i] = 0.f; return; }
  i -= P10;
  if (i < P11){ h1z[i] = 0.f; return; }
  i -= P11;
  if (i < P12){ slotz[i] = 0.f; return; }
}

// ---------------- fused GCN input: h0 = relu(x@W_in+b); out = h0@W1 ----------------
__global__ __launch_bounds__(256) void k_gcn01(const void* xseq, int t0, const int* flag,
    const float* b_inF, const short8* B1, const short8* B2, ushort* out)
{
  __shared__ __align__(16) ushort As[32*64];
  __shared__ __align__(16) ushort Xs[32*128];
  const int tid = threadIdx.x;
  const int bm  = blockIdx.x*32;
  const int tl  = blockIdx.y;
  {
    int row = tid>>3, seg = tid&7;
    int grow = bm + row;
    int colu = seg*8;
    V8 r;
    if (grow < NN){
      long base = ((long)(t0+tl)*NN + grow)*FF + colu;
      if (*flag){
        r.v = *(const short8*)((const ushort*)xseq + base);
      } else {
        const f32x4* s = (const f32x4*)((const float*)xseq + base);
        f32x4 f0 = s[0], f1 = s[1];
        #pragma unroll
        for (int j=0;j<4;j++){ r.u[j]=f2bu(f0[j]); r.u[4+j]=f2bu(f1[j]); }
      }
    } else {
      #pragma unroll
      for (int j=0;j<8;j++) r.u[j] = 0;
    }
    *(short8*)&As[row*64 + (colu ^ ((row&7)<<3))] = r.v;
  }
  __syncthreads();
  const int w = tid>>6, l = tid&63;
  f32x4 acc[2][2];
  #pragma unroll
  for (int i=0;i<2;i++)
    #pragma unroll
    for (int j=0;j<2;j++) acc[i][j] = (f32x4){0.f,0.f,0.f,0.f};
  #pragma unroll
  for (int ks=0; ks<2; ks++){
    short8 a[2], b[2];
    #pragma unroll
    for (int rt=0;rt<2;rt++){
      int row = rt*16 + (l&15);
      int colu = ks*32 + ((l>>4)<<3);
      a[rt] = *reinterpret_cast<const short8*>(&As[row*64 + (colu ^ ((row&7)<<3))]);
    }
    #pragma unroll
    for (int c2=0;c2<2;c2++) b[c2] = B1[(ks*8 + w*2+c2)*64 + l];
    #pragma unroll
    for (int rt=0;rt<2;rt++)
      #pragma unroll
      for (int c2=0;c2<2;c2++)
        acc[rt][c2] = __builtin_amdgcn_mfma_f32_16x16x32_bf16(a[rt], b[c2], acc[rt][c2], 0,0,0);
  }
  #pragma unroll
  for (int rt=0;rt<2;rt++)
    #pragma unroll
    for (int c2=0;c2<2;c2++){
      int col = w*32 + c2*16 + (l&15);
      #pragma unroll
      for (int reg=0;reg<4;reg++){
        int rl = rt*16 + ((l>>4)<<2) + reg;
        float v = fmaxf(acc[rt][c2][reg] + b_inF[col], 0.f);
        Xs[rl*128 + (col ^ ((rl&7)<<3))] = f2bu(v);
      }
    }
  __syncthreads();
  f32x4 acc1[2][2];
  #pragma unroll
  for (int i=0;i<2;i++)
    #pragma unroll
    for (int j=0;j<2;j++) acc1[i][j] = (f32x4){0.f,0.f,0.f,0.f};
  #pragma unroll
  for (int ks=0; ks<4; ks++){
    short8 a[2], b[2];
    #pragma unroll
    for (int rt=0;rt<2;rt++){
      int row = rt*16 + (l&15);
      int colu = ks*32 + ((l>>4)<<3);
      a[rt] = *reinterpret_cast<const short8*>(&Xs[row*128 + (colu ^ ((row&7)<<3))]);
    }
    #pragma unroll
    for (int c2=0;c2<2;c2++) b[c2] = B2[(ks*8 + w*2+c2)*64 + l];
    #pragma unroll
    for (int rt=0;rt<2;rt++)
      #pragma unroll
      for (int c2=0;c2<2;c2++)
        acc1[rt][c2] = __builtin_amdgcn_mfma_f32_16x16x32_bf16(a[rt], b[c2], acc1[rt][c2], 0,0,0);
  }
  #pragma unroll
  for (int rt=0;rt<2;rt++)
    #pragma unroll
    for (int c2=0;c2<2;c2++){
      int col = w*32 + c2*16 + (l&15);
      int slice = tl*2 + (col>>6);
      ushort* ob = out + (long)slice*SLICE_E + (col&63);
      #pragma unroll
      for (int reg=0;reg<4;reg++){
        int grow = bm + rt*16 + ((l>>4)<<2) + reg;
        __builtin_nontemporal_store(f2bu(acc1[rt][c2][reg]), ob + (long)grow*64);
      }
    }
}

// ---------------- batched GEMM2: out = (BN(A)+relu) @ W2, slice layout ----------------
__global__ __launch_bounds__(256) void k_mgemm2b(const ushort* Ain, const float* slots, int t0,
    const void* gw, const void* bew, const int* flag, const short8* B3, ushort* out)
{
  __shared__ __align__(16) ushort As[32*128];
  __shared__ float sc_s[HH], sh_s[HH];
  const int tid = threadIdx.x;
  const int bm  = blockIdx.x*32;
  const int tl  = blockIdx.y;
  const float* slot = slots + ((size_t)(t0+tl)*2 + 0)*2*HH;
  if (tid < HH){
    float mu  = slot[tid]*INVN;
    float var = fmaxf(slot[HH+tid]*INVN - mu*mu, 0.f);
    float sc  = rdf(gw, tid, *flag) * rsqrtf(var + BN_EPS);
    sc_s[tid] = sc;
    sh_s[tid] = rdf(bew, tid, *flag) - mu*sc;
  }
  __syncthreads();
  {
    int row = tid>>3, seg = tid&7;
    int grow = bm + row;
    #pragma unroll
    for (int i=0;i<2;i++){
      int colu = seg*16 + i*8;
      int slice = tl*2 + (colu>>6);
      V8 a; a.v = *(const short8*)(Ain + (long)slice*SLICE_E + (long)grow*64 + (colu&63));
      V8 r;
      #pragma unroll
      for (int j=0;j<8;j++){
        int k = colu + j;
        r.u[j] = f2bu(fmaxf(bu2f(a.u[j])*sc_s[k] + sh_s[k], 0.f));
      }
      *(short8*)&As[row*128 + (colu ^ ((row&7)<<3))] = r.v;
    }
  }
  __syncthreads();
  const int w = tid>>6, l = tid&63;
  f32x4 acc[2][2];
  #pragma unroll
  for (int i=0;i<2;i++)
    #pragma unroll
    for (int j=0;j<2;j++) acc[i][j] = (f32x4){0.f,0.f,0.f,0.f};
  #pragma unroll
  for (int ks=0; ks<4; ks++){
    short8 a[2], b[2];
    #pragma unroll
    for (int rt=0;rt<2;rt++){
      int row = rt*16 + (l&15);
      int colu = ks*32 + ((l>>4)<<3);
      a[rt] = *reinterpret_cast<const short8*>(&As[row*128 + (colu ^ ((row&7)<<3))]);
    }
    #pragma unroll
    for (int c2=0;c2<2;c2++) b[c2] = B3[(ks*8 + w*2+c2)*64 + l];
    #pragma unroll
    for (int rt=0;rt<2;rt++)
      #pragma unroll
      for (int c2=0;c2<2;c2++)
        acc[rt][c2] = __builtin_amdgcn_mfma_f32_16x16x32_bf16(a[rt], b[c2], acc[rt][c2], 0,0,0);
  }
  #pragma unroll
  for (int rt=0;rt<2;rt++)
    #pragma unroll
    for (int c2=0;c2<2;c2++){
      int col = w*32 + c2*16 + (l&15);
      int slice = tl*2 + (col>>6);
      ushort* ob = out + (long)slice*SLICE_E + (col&63);
      #pragma unroll
      for (int reg=0;reg<4;reg++){
        int grow = bm + rt*16 + ((l>>4)<<2) + reg;
        __builtin_nontemporal_store(f2bu(acc[rt][c2][reg]), ob + (long)grow*64);
      }
    }
}

// ---------------- fused double GRU step (per timestep; r12-proven shape) ----------------
__global__ __launch_bounds__(512) void k_gru2(const ushort* agg, int tt, const float* slots, int t,
    const void* gw, const void* bew, const int* flag,
    const ushort* h0prev, const ushort* h1prev,
    const short8* BG0, const short8* BG1,
    const float* bias4_0, const float* bias4_1,
    ushort* h0out, ushort* h1out)
{
  __shared__ __align__(16) ushort As[32*256];
  __shared__ float sc_s[HH], sh_s[HH];
  const int tid = threadIdx.x;
  const int bm  = blockIdx.x*32;
  const float* slot = slots + ((size_t)t*2 + 1)*2*HH;
  if (tid < HH){
    float mu  = slot[tid]*INVN;
    float var = fmaxf(slot[HH+tid]*INVN - mu*mu, 0.f);
    float sc  = rdf(gw, tid, *flag) * rsqrtf(var + BN_EPS);
    sc_s[tid] = sc;
    sh_s[tid] = rdf(bew, tid, *flag) - mu*sc;
  }
  __syncthreads();
  {
    int row = tid>>4, seg = tid&15;
    int grow = bm + row;
    #pragma unroll
    for (int i=0;i<2;i++){
      int colu = seg*16 + i*8;
      V8 r;
      if (colu < 128){
        int slice = tt*2 + (colu>>6);
        V8 a; a.v = *(const short8*)(agg + (long)slice*SLICE_E + (long)grow*64 + (colu&63));
        #pragma unroll
        for (int j=0;j<8;j++){
          int k = colu + j;
          r.u[j] = f2bu(fmaxf(bu2f(a.u[j])*sc_s[k] + sh_s[k], 0.f));
        }
      } else {
        r.v = *(const short8*)(h0prev + (long)grow*HH + (colu-128));
      }
      *(short8*)&As[row*256 + (colu ^ ((row&7)<<3))] = r.v;
    }
  }
  __syncthreads();
  const int w = tid>>6, l = tid&63;
  const int col = w*16 + (l&15);
  f32x4 acc[2][4];
  #pragma unroll
  for (int i=0;i<2;i++)
    #pragma unroll
    for (int g=0;g<4;g++) acc[i][g] = (f32x4){0.f,0.f,0.f,0.f};
  #pragma unroll
  for (int ks=0; ks<8; ks++){
    short8 a[2];
    #pragma unroll
    for (int rt=0;rt<2;rt++){
      int row = rt*16 + (l&15);
      int colu = ks*32 + ((l>>4)<<3);
      a[rt] = *reinterpret_cast<const short8*>(&As[row*256 + (colu ^ ((row&7)<<3))]);
    }
    #pragma unroll
    for (int g=0;g<4;g++){
      short8 b = BG0[(ks*32 + g*8 + w)*64 + l];
      acc[0][g] = __builtin_amdgcn_mfma_f32_16x16x32_bf16(a[0], b, acc[0][g], 0,0,0);
      acc[1][g] = __builtin_amdgcn_mfma_f32_16x16x32_bf16(a[1], b, acc[1][g], 0,0,0);
    }
  }
  __syncthreads();
  {
    float br = bias4_0[col], bz = bias4_0[HH+col], bi = bias4_0[2*HH+col], bh = bias4_0[3*HH+col];
    #pragma unroll
    for (int rt=0;rt<2;rt++)
      #pragma unroll
      for (int reg=0;reg<4;reg++){
        int rl = rt*16 + ((l>>4)<<2) + reg;
        int grow = bm + rl;
        float r = 1.f/(1.f + expf(-(acc[rt][0][reg] + br)));
        float z = 1.f/(1.f + expf(-(acc[rt][1][reg] + bz)));
        float nc = tanhf(acc[rt][2][reg] + bi + r*(acc[rt][3][reg] + bh));
        float hv = bu2f(h0prev[(long)grow*HH + col]);
        float hn = (1.f - z)*nc + z*hv;
        ushort hb = f2bu(hn);
        h0out[(long)grow*HH + col] = hb;
        As[rl*256 + (col ^ ((rl&7)<<3))] = hb;
      }
  }
  {
    int row = tid>>4, seg = tid&15;
    if (seg >= 8){
      int grow = bm + row;
      #pragma unroll
      for (int i=0;i<2;i++){
        int colu = seg*16 + i*8;
        V8 r; r.v = *(const short8*)(h1prev + (long)grow*HH + (colu-128));
        *(short8*)&As[row*256 + (colu ^ ((row&7)<<3))] = r.v;
      }
    }
  }
  __syncthreads();
  f32x4 acc1[2][4];
  #pragma unroll
  for (int i=0;i<2;i++)
    #pragma unroll
    for (int g=0;g<4;g++) acc1[i][g] = (f32x4){0.f,0.f,0.f,0.f};
  #pragma unroll
  for (int ks=0; ks<8; ks++){
    short8 a[2];
    #pragma unroll
    for (int rt=0;rt<2;rt++){
      int row = rt*16 + (l&15);
      int colu = ks*32 + ((l>>4)<<3);
      a[rt] = *reinterpret_cast<const short8*>(&As[row*256 + (colu ^ ((row&7)<<3))]);
    }
    #pragma unroll
    for (int g=0;g<4;g++){
      short8 b = BG1[(ks*32 + g*8 + w)*64 + l];
      acc1[0][g] = __builtin_amdgcn_mfma_f32_16x16x32_bf16(a[0], b, acc1[0][g], 0,0,0);
      acc1[1][g] = __builtin_amdgcn_mfma_f32_16x16x32_bf16(a[1], b, acc1[1][g], 0,0,0);
    }
  }
  {
    float br = bias4_1[col], bz = bias4_1[HH+col], bi = bias4_1[2*HH+col], bh = bias4_1[3*HH+col];
    #pragma unroll
    for (int rt=0;rt<2;rt++)
      #pragma unroll
      for (int reg=0;reg<4;reg++){
        int rl = rt*16 + ((l>>4)<<2) + reg;
        int grow = bm + rl;
        float r = 1.f/(1.f + expf(-(acc1[rt][0][reg] + br)));
        float z = 1.f/(1.f + expf(-(acc1[rt][1][reg] + bz)));
        float nc = tanhf(acc1[rt][2][reg] + bi + r*(acc1[rt][3][reg] + bh));
        float hv = bu2f(h1prev[(long)grow*HH + col]);
        h1out[(long)grow*HH + col] = f2bu((1.f - z)*nc + z*hv);
      }
  }
}

// ---------------- conv (CSR gather): same-edge both-halves, per-half slice ----------
// grid NBC*4, tl = bid&3. One node per wave; lanes 0-31 own slice 2tl, lanes 32-63 own
// slice 2tl+1 (loop-invariant per-lane base). ALL 64 lanes process the SAME edge ->
// e0/e1 wave-uniform, metadata in SGPRs (r13/r14 skeleton), NO cndmask, NO final shfl.
// Edge-visits halved (2.56M vs 5.12M) and ~5 VALU/edge vs ~15. Per-XCD working set
// 5.1 MB (2 slices) slightly exceeds 4 MB L2 -> some L3 traffic; HBM has headroom.
__global__ __launch_bounds__(256) void k_conv(const ushort* __restrict__ in,
    ushort* __restrict__ out, const int* __restrict__ offs,
    const int* __restrict__ csr_src, const float* __restrict__ csr_norm,
    const float* __restrict__ selfn)
{
  const int tl = blockIdx.x & 3;
  const int n  = (blockIdx.x >> 2)*4 + (threadIdx.x >> 6);
  const int l  = threadIdx.x & 63;
  const int half = l >> 5;
  const long sliceOff = (long)(tl*2 + half)*SLICE_E;
  const char* base = (const char*)(in + sliceOff) + (uint)(l & 31)*4u;
  uint selfu = *(const uint*)(base + (((uint)n)<<7));
  float sn = selfn[n];
  float ax = sn*blo(selfu), ay = sn*bhi(selfu);
  float ax2 = 0.f, ay2 = 0.f;
  const int e0 = __builtin_amdgcn_readfirstlane(offs[n]);
  const int e1 = __builtin_amdgcn_readfirstlane(offs[n+1]);
  int e = e0;
  for (; e + 8 <= e1; e += 8){
    int   s0 = csr_src[e+0], s1 = csr_src[e+1], s2 = csr_src[e+2], s3 = csr_src[e+3];
    int   s4 = csr_src[e+4], s5 = csr_src[e+5], s6 = csr_src[e+6], s7 = csr_src[e+7];
    float w0 = csr_norm[e+0], w1 = csr_norm[e+1], w2 = csr_norm[e+2], w3 = csr_norm[e+3];
    float w4 = csr_norm[e+4], w5 = csr_norm[e+5], w6 = csr_norm[e+6], w7 = csr_norm[e+7];
    uint u0 = *(const uint*)(base + (((uint)s0)<<7));
    uint u1 = *(const uint*)(base + (((uint)s1)<<7));
    uint u2 = *(const uint*)(base + (((uint)s2)<<7));
    uint u3 = *(const uint*)(base + (((uint)s3)<<7));
    uint u4 = *(const uint*)(base + (((uint)s4)<<7));
    uint u5 = *(const uint*)(base + (((uint)s5)<<7));
    uint u6 = *(const uint*)(base + (((uint)s6)<<7));
    uint u7 = *(const uint*)(base + (((uint)s7)<<7));
    ax  += w0*blo(u0) + w1*blo(u1);
    ay  += w0*bhi(u0) + w1*bhi(u1);
    ax2 += w2*blo(u2) + w3*blo(u3);
    ay2 += w2*bhi(u2) + w3*bhi(u3);
    ax  += w4*blo(u4) + w5*blo(u5);
    ay  += w4*bhi(u4) + w5*bhi(u5);
    ax2 += w6*blo(u6) + w7*blo(u7);
    ay2 += w6*bhi(u6) + w7*bhi(u7);
  }
  for (; e < e1; e++){
    int   s = csr_src[e];
    float w = csr_norm[e];
    uint u = *(const uint*)(base + (((uint)s)<<7));
    ax += w*blo(u); ay += w*bhi(u);
  }
  ax += ax2; ay += ay2;
  uint o = (uint)f2bu(ax) | ((uint)f2bu(ay) << 16);
  __builtin_nontemporal_store(o,
      (uint*)((char*)(out + sliceOff) + (((uint)n)<<7) + (uint)(l & 31)*4u));
}

// ---------------- BN stats into slot (t0+tl, layer), slice layout ----------------
__global__ __launch_bounds__(256) void k_bnstats(const ushort* x, float* slots, int t0, int layer){
  const int tl = blockIdx.y;
  float* slot = slots + ((size_t)(t0+tl)*2 + layer)*2*HH;
  int h = threadIdx.x & 127;
  int g = threadIdx.x >> 7;
  int slice = tl*2 + (h>>6);
  const ushort* base = x + (long)slice*SLICE_E + (h&63);
  float s = 0.f, ss = 0.f;
  for (int r = blockIdx.x*2 + g; r < NN; r += gridDim.x*2){
    float v = bu2f(base[(long)r*64]);
    s += v; ss += v*v;
  }
  __shared__ float sh[2][HH], shq[2][HH];
  sh[g][h] = s; shq[g][h] = ss;
  __syncthreads();
  if (g == 0){
    atomicAdd(&slot[h],    sh[0][h] + sh[1][h]);
    atomicAdd(&slot[HH+h], shq[0][h] + shq[1][h]);
  }
}

// ---------------- output head (bf16 h input) ----------------
__global__ void k_out(const ushort* h, const float* Wo, const float* bo, void* out, int n,
                      const int* flag){
  __shared__ float Ws[HH][CC+1];
  __shared__ float bs[CC];
  int tid = threadIdx.x;
  for (int i = tid; i < HH*CC; i += 256) Ws[i/CC][i%CC] = Wo[i];
  if (tid < CC) bs[tid] = bo[tid];
  __syncthreads();
  int row = blockIdx.x*16 + (tid >> 4);
  int c   = tid & 15;
  if (row >= n) return;
  const ushort* hr = h + (size_t)row*HH;
  float s = bs[c];
  #pragma unroll 8
  for (int j = 0; j < HH; j++) s += bu2f(hr[j])*Ws[j][c];
  float m = s;
  for (int o = 8; o; o >>= 1) m = fmaxf(m, __shfl_xor(m, o, 16));
  float e = expf(s - m);
  float sum = e;
  for (int o = 8; o; o >>= 1) sum += __shfl_xor(sum, o, 16);
  float v = s - m - logf(sum);
  size_t idx = (size_t)row*CC + c;
  if (*flag) ((bf16*)out)[idx] = __float2bfloat16(v);
  else       ((float*)out)[idx] = v;
}

// ---------------- launcher ----------------
static inline size_t alignup(size_t x){ return (x + 255) & ~(size_t)255; }
static inline int ceil_div(int a, int b){ return (a + b - 1)/b; }

extern "C" void kernel_launch(void* const* d_in, const int* in_sizes, int n_in,
                              void* d_out, int out_size, void* d_ws, size_t ws_size,
                              hipStream_t stream){
  const void* x_seq = d_in[0];
  const int*  eidx  = (const int*)d_in[1];
  const void* ew    = d_in[2];
  const void* W_in  = d_in[3];
  const void* b_in  = d_in[4];
  const void* W1    = d_in[5];
  // d_in[6] = bc1 : cancels under training-mode BN
  const void* g1    = d_in[7];
  const void* be1   = d_in[8];
  const void* W2    = d_in[9];
  // d_in[10] = bc2 : cancels under BN
  const void* g2    = d_in[11];
  const void* be2   = d_in[12];
  const void* Wih0  = d_in[13];
  const void* Whh0  = d_in[14];
  const void* bih0  = d_in[15];
  const void* bhh0  = d_in[16];
  const void* Wih1  = d_in[17];
  const void* Whh1  = d_in[18];
  const void* bih1  = d_in[19];
  const void* bhh1  = d_in[20];
  const void* W_out = d_in[21];
  const void* b_out = d_in[22];
  const int* src = eidx;
  const int* dst = eidx + EE;

  // workspace (~90 MB)
  char* p = (char*)d_ws;
  auto alloc = [&](size_t bytes)->void*{ void* r = (void*)p; p += alignup(bytes); return r; };
  int*   flag     = (int*)  alloc(4);
  ull*   deg64    = (ull*)  alloc((size_t)NN*8);
  float* dinv     = (float*)alloc(NN*4);
  float* selfn    = (float*)alloc(NN*4);
  int*   cnt      = (int*)  alloc(NN*4);
  int*   cursor   = (int*)  alloc(NN*4);
  int*   offs     = (int*)  alloc((NN+1)*4);
  int*   csr_src  = (int*)  alloc((size_t)EE*4);
  float* csr_norm = (float*)alloc((size_t)EE*4);
  ushort* B1sw  = (ushort*)alloc((size_t)P0*2);
  ushort* B2sw  = (ushort*)alloc((size_t)P1*2);
  ushort* B3sw  = (ushort*)alloc((size_t)P2*2);
  ushort* BG0sw = (ushort*)alloc((size_t)P3*2);
  ushort* BG1sw = (ushort*)alloc((size_t)P4*2);
  float* bias4_0 = (float*)alloc(4*HH*4);
  float* bias4_1 = (float*)alloc(4*HH*4);
  float* b_inF   = (float*)alloc(HH*4);
  float* W_outF  = (float*)alloc(HH*CC*4);
  float* b_outF  = (float*)alloc(CC*4);
  float* slots   = (float*)alloc((size_t)T_STEPS*2*2*HH*4);
  ushort* temp2b = (ushort*)alloc((size_t)8*SLICE_E*2);
  ushort* agg1b  = (ushort*)alloc((size_t)8*SLICE_E*2);
  ushort* agg2b  = (ushort*)alloc((size_t)8*SLICE_E*2);
  ushort* h0bufA = (ushort*)alloc((size_t)M_PAD*HH*2);
  ushort* h0bufB = (ushort*)alloc((size_t)M_PAD*HH*2);
  ushort* h1bufA = (ushort*)alloc((size_t)M_PAD*HH*2);
  ushort* h1bufB = (ushort*)alloc((size_t)M_PAD*HH*2);
  (void)ws_size; (void)n_in; (void)in_sizes; (void)out_size;

  const int TPB = 256;
  // ---- init (+probe in block 0), graph setup ----
  k_init2<<<ceil_div(NN,TPB), TPB, 0, stream>>>(x_seq, flag, deg64, cursor, NN);
  k_prep<<<ceil_div(PREP_TOT,TPB), TPB, 0, stream>>>(
      W_in, W1, W2, Wih0, Whh0, Wih1, Whh1, bih0, bhh0, bih1, bhh1,
      b_in, W_out, b_out,
      B1sw, B2sw, B3sw, BG0sw, BG1sw,
      bias4_0, bias4_1, b_inF, W_outF, b_outF,
      (float*)h0bufA, (float*)h1bufA, slots, flag);
  k_deg <<<ceil_div(EE,TPB), TPB, 0, stream>>>(dst, ew, deg64, EE, flag);
  k_dinv<<<ceil_div(NN,TPB), TPB, 0, stream>>>(deg64, dinv, selfn, cnt, NN);
  k_scan<<<1, 256, 0, stream>>>(cnt, offs, NN);
  k_fill<<<ceil_div(EE,TPB), TPB, 0, stream>>>(src, dst, ew, dinv, offs, cursor, csr_src, csr_norm, EE, flag);

  ushort* H0[2] = {h0bufA, h0bufB};
  ushort* H1[2] = {h1bufA, h1bufB};
  int cur = 0;

  // ---- main loop: 4 chunks of 4 timesteps ----
  for (int c = 0; c < NCHUNK; c++){
    int t0 = c*T_CHUNK;
    dim3 gg(NB32, T_CHUNK);
    dim3 gb(128, T_CHUNK);
    k_gcn01 <<<gg, 256, 0, stream>>>(x_seq, t0, flag, b_inF, (const short8*)B1sw, (const short8*)B2sw, temp2b);
    k_conv  <<<NBC*4, 256, 0, stream>>>(temp2b, agg1b, offs, csr_src, csr_norm, selfn);
    k_bnstats<<<gb, 256, 0, stream>>>(agg1b, slots, t0, 0);
    k_mgemm2b<<<gg, 256, 0, stream>>>(agg1b, slots, t0, g1, be1, flag, (const short8*)B3sw, temp2b);
    k_conv  <<<NBC*4, 256, 0, stream>>>(temp2b, agg2b, offs, csr_src, csr_norm, selfn);
    k_bnstats<<<gb, 256, 0, stream>>>(agg2b, slots, t0, 1);
    for (int tt = 0; tt < T_CHUNK; tt++){
      int t = t0 + tt;
      int nxt = cur ^ 1;
      k_gru2<<<NB32, 512, 0, stream>>>(agg2b, tt, slots, t,
                                       g2, be2, flag, H0[cur], H1[cur],
                                       (const short8*)BG0sw, (const short8*)BG1sw,
                                       bias4_0, bias4_1, H0[nxt], H1[nxt]);
      cur = nxt;
    }
  }

  // ---- output head ----
  k_out<<<ceil_div(NN,16), 256, 0, stream>>>(H1[cur], W_outF, b_outF, d_out, NN, flag);
}

// Round 19
// 1354.795 us; speedup vs baseline: 1.9373x; 1.0782x over previous
//
#include <hip/hip_runtime.h>
#include <hip/hip_bf16.h>
#include <stdint.h>

#define T_STEPS 16
#define T_CHUNK 4
#define NCHUNK  4
#define NN      20000
#define M_PAD   20032     // 626 * 32
#define NB32    626
#define NBC     5000      // conv blocks per tl (4 nodes each)
#define EE      640000
#define FF      64
#define HH      128
#define CC      16
#define BN_EPS  1e-5f
#define INVN    (1.0f/(float)NN)
#define SLICE_E ((long)M_PAD*64)

typedef __hip_bfloat16 bf16;
typedef unsigned long long ull;
typedef __attribute__((ext_vector_type(8))) short short8;
typedef __attribute__((ext_vector_type(4))) float f32x4;

union V8 { short8 v; ushort u[8]; };

__device__ __forceinline__ float rdf(const void* p, long i, int isbf){
  return isbf ? __bfloat162float(((const bf16*)p)[i]) : ((const float*)p)[i];
}
__device__ __forceinline__ ushort f2bu(float f){
  bf16 h = __float2bfloat16(f);
  return *reinterpret_cast<ushort*>(&h);
}
__device__ __forceinline__ float bu2f(ushort u){
  return __uint_as_float((uint)u << 16);
}
__device__ __forceinline__ float blo(uint u){ return __uint_as_float(u << 16); }
__device__ __forceinline__ float bhi(uint u){ return __uint_as_float(u & 0xffff0000u); }

// ---------------- init + dtype probe (block 0 probes; all blocks init) --------------
__global__ void k_init2(const void* x, int* flag, ull* deg64, int* cursor, int n){
  int i = blockIdx.x*blockDim.x + threadIdx.x;
  if (blockIdx.x == 0){
    __shared__ int sh[256];
    int tid = threadIdx.x;
    const uint16_t* u = (const uint16_t*)x;
    uint16_t v = u[2*tid];
    int e = (v >> 7) & 0xFF;
    sh[tid] = (e >= 120 && e <= 134) ? 1 : 0;
    __syncthreads();
    for (int o = 128; o; o >>= 1){ if (tid < o) sh[tid] += sh[tid+o]; __syncthreads(); }
    if (tid == 0) flag[0] = (sh[0] >= 128) ? 1 : 0;
  }
  if (i < n){ deg64[i] = (ull)(1u<<20); cursor[i] = 0; }
}

// ---------------- graph setup ----------------
__global__ void k_deg(const int* dst, const void* w, ull* deg64, int e, const int* flag){
  int i = blockIdx.x*blockDim.x + threadIdx.x;
  if (i < e){
    float wv = rdf(w, i, *flag);
    ull pk = (1ULL<<32) | (ull)(uint)(wv*1048576.0f + 0.5f);
    atomicAdd(&deg64[dst[i]], pk);
  }
}
__global__ void k_dinv(const ull* deg64, float* dinv, float* selfnorm, int* cnt, int n){
  int i = blockIdx.x*blockDim.x + threadIdx.x;
  if (i < n){
    ull v = deg64[i];
    float d = (float)(uint)(v & 0xffffffffULL) * (1.0f/1048576.0f);
    cnt[i] = (int)(v >> 32);
    float r = d > 0.f ? rsqrtf(d) : 0.f;
    dinv[i] = r; selfnorm[i] = r*r;
  }
}
__global__ void k_scan(const int* cnt, int* offs, int n){
  __shared__ int part[256];
  int tid = threadIdx.x;
  int chunk = (n + 255)/256;
  int lo = tid*chunk; int hi = lo + chunk;
  if (hi > n) hi = n;
  if (lo > n) lo = n;
  int s = 0;
  for (int i = lo; i < hi; i++) s += cnt[i];
  part[tid] = s;
  __syncthreads();
  for (int off = 1; off < 256; off <<= 1){
    int t = (tid >= off) ? part[tid-off] : 0;
    __syncthreads();
    part[tid] += t;
    __syncthreads();
  }
  int run = part[tid] - s;
  for (int i = lo; i < hi; i++){ offs[i] = run; run += cnt[i]; }
  if (tid == 255) offs[n] = part[255];
}
__global__ void k_fill(const int* src, const int* dst, const void* w, const float* dinv,
                       const int* offs, int* cursor, int* csr_src, float* csr_norm, int e,
                       const int* flag){
  int i = blockIdx.x*blockDim.x + threadIdx.x;
  if (i < e){
    int s = src[i], d = dst[i];
    int pos = offs[d] + atomicAdd(&cursor[d], 1);
    csr_src[pos]  = s;
    csr_norm[pos] = dinv[s] * rdf(w, i, *flag) * dinv[d];
  }
}

// ---------------- weight swizzle value (device fn) ----------------
__device__ float swz_val(const void* s1, const void* s2, int K, int N, int mode,
                         int o, int isbf){
  int nct = N/16;
  int ks = o / (nct*512);
  int r1 = o % (nct*512);
  int ct = r1 / 512;
  int r2 = r1 % 512;
  int l  = r2 >> 3;
  int j  = r2 & 7;
  int k  = ks*32 + ((l>>4)<<3) + j;
  int c  = ct*16 + (l&15);
  if (mode == 0) return rdf(s1, (long)k*N + c, isbf);
  if (k < HH){
    if (c < 3*HH) return rdf(s1, (long)c*HH + k, isbf);
    return 0.f;
  }
  int kh = k - HH;
  if (c < 2*HH)      return rdf(s2, (long)c*HH + kh, isbf);
  if (c < 3*HH)      return 0.f;
  return rdf(s2, (long)(c-HH)*HH + kh, isbf);
}
__device__ float bias4_val(const void* bih, const void* bhh, int c, int isbf){
  if (c < 2*HH) return rdf(bih, c, isbf) + rdf(bhh, c, isbf);
  if (c < 3*HH) return rdf(bih, c, isbf);
  return rdf(bhh, c - HH, isbf);
}

// ---------------- unified prep kernel ----------------
#define P0 8192
#define P1 16384
#define P2 16384
#define P3 131072
#define P4 131072
#define P5 512
#define P6 512
#define P7 128
#define P8 2048
#define P9 16
#define P10 (M_PAD*HH/2)
#define P11 (M_PAD*HH/2)
#define P12 (T_STEPS*2*2*HH)
#define PREP_TOT (P0+P1+P2+P3+P4+P5+P6+P7+P8+P9+P10+P11+P12)
__global__ __launch_bounds__(256) void k_prep(
    const void* W_in, const void* W1, const void* W2,
    const void* Wih0, const void* Whh0, const void* Wih1, const void* Whh1,
    const void* bih0, const void* bhh0, const void* bih1, const void* bhh1,
    const void* b_in, const void* W_out, const void* b_out,
    ushort* B1sw, ushort* B2sw, ushort* B3sw, ushort* BG0sw, ushort* BG1sw,
    float* bias4_0, float* bias4_1, float* b_inF, float* W_outF, float* b_outF,
    float* h0z, float* h1z, float* slotz, const int* flag)
{
  long i = (long)blockIdx.x*256 + threadIdx.x;
  int isbf = *flag;
  if (i < P0){ B1sw[i] = f2bu(swz_val(W_in, nullptr, FF, HH, 0, (int)i, isbf)); return; }
  i -= P0;
  if (i < P1){ B2sw[i] = f2bu(swz_val(W1, nullptr, HH, HH, 0, (int)i, isbf)); return; }
  i -= P1;
  if (i < P2){ B3sw[i] = f2bu(swz_val(W2, nullptr, HH, HH, 0, (int)i, isbf)); return; }
  i -= P2;
  if (i < P3){ BG0sw[i] = f2bu(swz_val(Wih0, Whh0, 2*HH, 4*HH, 1, (int)i, isbf)); return; }
  i -= P3;
  if (i < P4){ BG1sw[i] = f2bu(swz_val(Wih1, Whh1, 2*HH, 4*HH, 1, (int)i, isbf)); return; }
  i -= P4;
  if (i < P5){ bias4_0[i] = bias4_val(bih0, bhh0, (int)i, isbf); return; }
  i -= P5;
  if (i < P6){ bias4_1[i] = bias4_val(bih1, bhh1, (int)i, isbf); return; }
  i -= P6;
  if (i < P7){ b_inF[i] = rdf(b_in, i, isbf); return; }
  i -= P7;
  if (i < P8){ W_outF[i] = rdf(W_out, i, isbf); return; }
  i -= P8;
  if (i < P9){ b_outF[i] = rdf(b_out, i, isbf); return; }
  i -= P9;
  if (i < P10){ h0z[i] = 0.f; return; }
  i -= P10;
  if (i < P11){ h1z[i] = 0.f; return; }
  i -= P11;
  if (i < P12){ slotz[i] = 0.f; return; }
}

// ---------------- fused GCN input: h0 = relu(x@W_in+b); out = h0@W1 ----------------
__global__ __launch_bounds__(256) void k_gcn01(const void* xseq, int t0, const int* flag,
    const float* b_inF, const short8* B1, const short8* B2, ushort* out)
{
  __shared__ __align__(16) ushort As[32*64];
  __shared__ __align__(16) ushort Xs[32*128];
  const int tid = threadIdx.x;
  const int bm  = blockIdx.x*32;
  const int tl  = blockIdx.y;
  {
    int row = tid>>3, seg = tid&7;
    int grow = bm + row;
    int colu = seg*8;
    V8 r;
    if (grow < NN){
      long base = ((long)(t0+tl)*NN + grow)*FF + colu;
      if (*flag){
        r.v = *(const short8*)((const ushort*)xseq + base);
      } else {
        const f32x4* s = (const f32x4*)((const float*)xseq + base);
        f32x4 f0 = s[0], f1 = s[1];
        #pragma unroll
        for (int j=0;j<4;j++){ r.u[j]=f2bu(f0[j]); r.u[4+j]=f2bu(f1[j]); }
      }
    } else {
      #pragma unroll
      for (int j=0;j<8;j++) r.u[j] = 0;
    }
    *(short8*)&As[row*64 + (colu ^ ((row&7)<<3))] = r.v;
  }
  __syncthreads();
  const int w = tid>>6, l = tid&63;
  f32x4 acc[2][2];
  #pragma unroll
  for (int i=0;i<2;i++)
    #pragma unroll
    for (int j=0;j<2;j++) acc[i][j] = (f32x4){0.f,0.f,0.f,0.f};
  #pragma unroll
  for (int ks=0; ks<2; ks++){
    short8 a[2], b[2];
    #pragma unroll
    for (int rt=0;rt<2;rt++){
      int row = rt*16 + (l&15);
      int colu = ks*32 + ((l>>4)<<3);
      a[rt] = *reinterpret_cast<const short8*>(&As[row*64 + (colu ^ ((row&7)<<3))]);
    }
    #pragma unroll
    for (int c2=0;c2<2;c2++) b[c2] = B1[(ks*8 + w*2+c2)*64 + l];
    #pragma unroll
    for (int rt=0;rt<2;rt++)
      #pragma unroll
      for (int c2=0;c2<2;c2++)
        acc[rt][c2] = __builtin_amdgcn_mfma_f32_16x16x32_bf16(a[rt], b[c2], acc[rt][c2], 0,0,0);
  }
  #pragma unroll
  for (int rt=0;rt<2;rt++)
    #pragma unroll
    for (int c2=0;c2<2;c2++){
      int col = w*32 + c2*16 + (l&15);
      #pragma unroll
      for (int reg=0;reg<4;reg++){
        int rl = rt*16 + ((l>>4)<<2) + reg;
        float v = fmaxf(acc[rt][c2][reg] + b_inF[col], 0.f);
        Xs[rl*128 + (col ^ ((rl&7)<<3))] = f2bu(v);
      }
    }
  __syncthreads();
  f32x4 acc1[2][2];
  #pragma unroll
  for (int i=0;i<2;i++)
    #pragma unroll
    for (int j=0;j<2;j++) acc1[i][j] = (f32x4){0.f,0.f,0.f,0.f};
  #pragma unroll
  for (int ks=0; ks<4; ks++){
    short8 a[2], b[2];
    #pragma unroll
    for (int rt=0;rt<2;rt++){
      int row = rt*16 + (l&15);
      int colu = ks*32 + ((l>>4)<<3);
      a[rt] = *reinterpret_cast<const short8*>(&Xs[row*128 + (colu ^ ((row&7)<<3))]);
    }
    #pragma unroll
    for (int c2=0;c2<2;c2++) b[c2] = B2[(ks*8 + w*2+c2)*64 + l];
    #pragma unroll
    for (int rt=0;rt<2;rt++)
      #pragma unroll
      for (int c2=0;c2<2;c2++)
        acc1[rt][c2] = __builtin_amdgcn_mfma_f32_16x16x32_bf16(a[rt], b[c2], acc1[rt][c2], 0,0,0);
  }
  #pragma unroll
  for (int rt=0;rt<2;rt++)
    #pragma unroll
    for (int c2=0;c2<2;c2++){
      int col = w*32 + c2*16 + (l&15);
      int slice = tl*2 + (col>>6);
      ushort* ob = out + (long)slice*SLICE_E + (col&63);
      #pragma unroll
      for (int reg=0;reg<4;reg++){
        int grow = bm + rt*16 + ((l>>4)<<2) + reg;
        ob[(long)grow*64] = f2bu(acc1[rt][c2][reg]);   // cached store: keep tile L3-resident
      }
    }
}

// ---------------- batched GEMM2: out = (BN(A)+relu) @ W2, slice layout ----------------
__global__ __launch_bounds__(256) void k_mgemm2b(const ushort* Ain, const float* slots, int t0,
    const void* gw, const void* bew, const int* flag, const short8* B3, ushort* out)
{
  __shared__ __align__(16) ushort As[32*128];
  __shared__ float sc_s[HH], sh_s[HH];
  const int tid = threadIdx.x;
  const int bm  = blockIdx.x*32;
  const int tl  = blockIdx.y;
  const float* slot = slots + ((size_t)(t0+tl)*2 + 0)*2*HH;
  if (tid < HH){
    float mu  = slot[tid]*INVN;
    float var = fmaxf(slot[HH+tid]*INVN - mu*mu, 0.f);
    float sc  = rdf(gw, tid, *flag) * rsqrtf(var + BN_EPS);
    sc_s[tid] = sc;
    sh_s[tid] = rdf(bew, tid, *flag) - mu*sc;
  }
  __syncthreads();
  {
    int row = tid>>3, seg = tid&7;
    int grow = bm + row;
    #pragma unroll
    for (int i=0;i<2;i++){
      int colu = seg*16 + i*8;
      int slice = tl*2 + (colu>>6);
      V8 a; a.v = *(const short8*)(Ain + (long)slice*SLICE_E + (long)grow*64 + (colu&63));
      V8 r;
      #pragma unroll
      for (int j=0;j<8;j++){
        int k = colu + j;
        r.u[j] = f2bu(fmaxf(bu2f(a.u[j])*sc_s[k] + sh_s[k], 0.f));
      }
      *(short8*)&As[row*128 + (colu ^ ((row&7)<<3))] = r.v;
    }
  }
  __syncthreads();
  const int w = tid>>6, l = tid&63;
  f32x4 acc[2][2];
  #pragma unroll
  for (int i=0;i<2;i++)
    #pragma unroll
    for (int j=0;j<2;j++) acc[i][j] = (f32x4){0.f,0.f,0.f,0.f};
  #pragma unroll
  for (int ks=0; ks<4; ks++){
    short8 a[2], b[2];
    #pragma unroll
    for (int rt=0;rt<2;rt++){
      int row = rt*16 + (l&15);
      int colu = ks*32 + ((l>>4)<<3);
      a[rt] = *reinterpret_cast<const short8*>(&As[row*128 + (colu ^ ((row&7)<<3))]);
    }
    #pragma unroll
    for (int c2=0;c2<2;c2++) b[c2] = B3[(ks*8 + w*2+c2)*64 + l];
    #pragma unroll
    for (int rt=0;rt<2;rt++)
      #pragma unroll
      for (int c2=0;c2<2;c2++)
        acc[rt][c2] = __builtin_amdgcn_mfma_f32_16x16x32_bf16(a[rt], b[c2], acc[rt][c2], 0,0,0);
  }
  #pragma unroll
  for (int rt=0;rt<2;rt++)
    #pragma unroll
    for (int c2=0;c2<2;c2++){
      int col = w*32 + c2*16 + (l&15);
      int slice = tl*2 + (col>>6);
      ushort* ob = out + (long)slice*SLICE_E + (col&63);
      #pragma unroll
      for (int reg=0;reg<4;reg++){
        int grow = bm + rt*16 + ((l>>4)<<2) + reg;
        ob[(long)grow*64] = f2bu(acc[rt][c2][reg]);    // cached store
      }
    }
}

// ---------------- fused double GRU step (per timestep; r12-proven shape) ----------------
__global__ __launch_bounds__(512) void k_gru2(const ushort* agg, int tt, const float* slots, int t,
    const void* gw, const void* bew, const int* flag,
    const ushort* h0prev, const ushort* h1prev,
    const short8* BG0, const short8* BG1,
    const float* bias4_0, const float* bias4_1,
    ushort* h0out, ushort* h1out)
{
  __shared__ __align__(16) ushort As[32*256];
  __shared__ float sc_s[HH], sh_s[HH];
  const int tid = threadIdx.x;
  const int bm  = blockIdx.x*32;
  const float* slot = slots + ((size_t)t*2 + 1)*2*HH;
  if (tid < HH){
    float mu  = slot[tid]*INVN;
    float var = fmaxf(slot[HH+tid]*INVN - mu*mu, 0.f);
    float sc  = rdf(gw, tid, *flag) * rsqrtf(var + BN_EPS);
    sc_s[tid] = sc;
    sh_s[tid] = rdf(bew, tid, *flag) - mu*sc;
  }
  __syncthreads();
  {
    int row = tid>>4, seg = tid&15;
    int grow = bm + row;
    #pragma unroll
    for (int i=0;i<2;i++){
      int colu = seg*16 + i*8;
      V8 r;
      if (colu < 128){
        int slice = tt*2 + (colu>>6);
        V8 a; a.v = *(const short8*)(agg + (long)slice*SLICE_E + (long)grow*64 + (colu&63));
        #pragma unroll
        for (int j=0;j<8;j++){
          int k = colu + j;
          r.u[j] = f2bu(fmaxf(bu2f(a.u[j])*sc_s[k] + sh_s[k], 0.f));
        }
      } else {
        r.v = *(const short8*)(h0prev + (long)grow*HH + (colu-128));
      }
      *(short8*)&As[row*256 + (colu ^ ((row&7)<<3))] = r.v;
    }
  }
  __syncthreads();
  const int w = tid>>6, l = tid&63;
  const int col = w*16 + (l&15);
  f32x4 acc[2][4];
  #pragma unroll
  for (int i=0;i<2;i++)
    #pragma unroll
    for (int g=0;g<4;g++) acc[i][g] = (f32x4){0.f,0.f,0.f,0.f};
  #pragma unroll
  for (int ks=0; ks<8; ks++){
    short8 a[2];
    #pragma unroll
    for (int rt=0;rt<2;rt++){
      int row = rt*16 + (l&15);
      int colu = ks*32 + ((l>>4)<<3);
      a[rt] = *reinterpret_cast<const short8*>(&As[row*256 + (colu ^ ((row&7)<<3))]);
    }
    #pragma unroll
    for (int g=0;g<4;g++){
      short8 b = BG0[(ks*32 + g*8 + w)*64 + l];
      acc[0][g] = __builtin_amdgcn_mfma_f32_16x16x32_bf16(a[0], b, acc[0][g], 0,0,0);
      acc[1][g] = __builtin_amdgcn_mfma_f32_16x16x32_bf16(a[1], b, acc[1][g], 0,0,0);
    }
  }
  __syncthreads();
  {
    float br = bias4_0[col], bz = bias4_0[HH+col], bi = bias4_0[2*HH+col], bh = bias4_0[3*HH+col];
    #pragma unroll
    for (int rt=0;rt<2;rt++)
      #pragma unroll
      for (int reg=0;reg<4;reg++){
        int rl = rt*16 + ((l>>4)<<2) + reg;
        int grow = bm + rl;
        float r = 1.f/(1.f + expf(-(acc[rt][0][reg] + br)));
        float z = 1.f/(1.f + expf(-(acc[rt][1][reg] + bz)));
        float nc = tanhf(acc[rt][2][reg] + bi + r*(acc[rt][3][reg] + bh));
        float hv = bu2f(h0prev[(long)grow*HH + col]);
        float hn = (1.f - z)*nc + z*hv;
        ushort hb = f2bu(hn);
        h0out[(long)grow*HH + col] = hb;
        As[rl*256 + (col ^ ((rl&7)<<3))] = hb;
      }
  }
  {
    int row = tid>>4, seg = tid&15;
    if (seg >= 8){
      int grow = bm + row;
      #pragma unroll
      for (int i=0;i<2;i++){
        int colu = seg*16 + i*8;
        V8 r; r.v = *(const short8*)(h1prev + (long)grow*HH + (colu-128));
        *(short8*)&As[row*256 + (colu ^ ((row&7)<<3))] = r.v;
      }
    }
  }
  __syncthreads();
  f32x4 acc1[2][4];
  #pragma unroll
  for (int i=0;i<2;i++)
    #pragma unroll
    for (int g=0;g<4;g++) acc1[i][g] = (f32x4){0.f,0.f,0.f,0.f};
  #pragma unroll
  for (int ks=0; ks<8; ks++){
    short8 a[2];
    #pragma unroll
    for (int rt=0;rt<2;rt++){
      int row = rt*16 + (l&15);
      int colu = ks*32 + ((l>>4)<<3);
      a[rt] = *reinterpret_cast<const short8*>(&As[row*256 + (colu ^ ((row&7)<<3))]);
    }
    #pragma unroll
    for (int g=0;g<4;g++){
      short8 b = BG1[(ks*32 + g*8 + w)*64 + l];
      acc1[0][g] = __builtin_amdgcn_mfma_f32_16x16x32_bf16(a[0], b, acc1[0][g], 0,0,0);
      acc1[1][g] = __builtin_amdgcn_mfma_f32_16x16x32_bf16(a[1], b, acc1[1][g], 0,0,0);
    }
  }
  {
    float br = bias4_1[col], bz = bias4_1[HH+col], bi = bias4_1[2*HH+col], bh = bias4_1[3*HH+col];
    #pragma unroll
    for (int rt=0;rt<2;rt++)
      #pragma unroll
      for (int reg=0;reg<4;reg++){
        int rl = rt*16 + ((l>>4)<<2) + reg;
        int grow = bm + rl;
        float r = 1.f/(1.f + expf(-(acc1[rt][0][reg] + br)));
        float z = 1.f/(1.f + expf(-(acc1[rt][1][reg] + bz)));
        float nc = tanhf(acc1[rt][2][reg] + bi + r*(acc1[rt][3][reg] + bh));
        float hv = bu2f(h1prev[(long)grow*HH + col]);
        h1out[(long)grow*HH + col] = f2bu((1.f - z)*nc + z*hv);
      }
  }
}

// ---------------- conv (CSR gather): same-edge both-halves, per-half slice ----------
// r18 structure; stores now CACHED (r19: keep tiles L3-resident, cut HBM re-fetch).
__global__ __launch_bounds__(256) void k_conv(const ushort* __restrict__ in,
    ushort* __restrict__ out, const int* __restrict__ offs,
    const int* __restrict__ csr_src, const float* __restrict__ csr_norm,
    const float* __restrict__ selfn)
{
  const int tl = blockIdx.x & 3;
  const int n  = (blockIdx.x >> 2)*4 + (threadIdx.x >> 6);
  const int l  = threadIdx.x & 63;
  const int half = l >> 5;
  const long sliceOff = (long)(tl*2 + half)*SLICE_E;
  const char* base = (const char*)(in + sliceOff) + (uint)(l & 31)*4u;
  uint selfu = *(const uint*)(base + (((uint)n)<<7));
  float sn = selfn[n];
  float ax = sn*blo(selfu), ay = sn*bhi(selfu);
  float ax2 = 0.f, ay2 = 0.f;
  const int e0 = __builtin_amdgcn_readfirstlane(offs[n]);
  const int e1 = __builtin_amdgcn_readfirstlane(offs[n+1]);
  int e = e0;
  for (; e + 8 <= e1; e += 8){
    int   s0 = csr_src[e+0], s1 = csr_src[e+1], s2 = csr_src[e+2], s3 = csr_src[e+3];
    int   s4 = csr_src[e+4], s5 = csr_src[e+5], s6 = csr_src[e+6], s7 = csr_src[e+7];
    float w0 = csr_norm[e+0], w1 = csr_norm[e+1], w2 = csr_norm[e+2], w3 = csr_norm[e+3];
    float w4 = csr_norm[e+4], w5 = csr_norm[e+5], w6 = csr_norm[e+6], w7 = csr_norm[e+7];
    uint u0 = *(const uint*)(base + (((uint)s0)<<7));
    uint u1 = *(const uint*)(base + (((uint)s1)<<7));
    uint u2 = *(const uint*)(base + (((uint)s2)<<7));
    uint u3 = *(const uint*)(base + (((uint)s3)<<7));
    uint u4 = *(const uint*)(base + (((uint)s4)<<7));
    uint u5 = *(const uint*)(base + (((uint)s5)<<7));
    uint u6 = *(const uint*)(base + (((uint)s6)<<7));
    uint u7 = *(const uint*)(base + (((uint)s7)<<7));
    ax  += w0*blo(u0) + w1*blo(u1);
    ay  += w0*bhi(u0) + w1*bhi(u1);
    ax2 += w2*blo(u2) + w3*blo(u3);
    ay2 += w2*bhi(u2) + w3*bhi(u3);
    ax  += w4*blo(u4) + w5*blo(u5);
    ay  += w4*bhi(u4) + w5*bhi(u5);
    ax2 += w6*blo(u6) + w7*blo(u7);
    ay2 += w6*bhi(u6) + w7*bhi(u7);
  }
  for (; e < e1; e++){
    int   s = csr_src[e];
    float w = csr_norm[e];
    uint u = *(const uint*)(base + (((uint)s)<<7));
    ax += w*blo(u); ay += w*bhi(u);
  }
  ax += ax2; ay += ay2;
  uint o = (uint)f2bu(ax) | ((uint)f2bu(ay) << 16);
  *(uint*)((char*)(out + sliceOff) + (((uint)n)<<7) + (uint)(l & 31)*4u) = o;  // cached
}

// ---------------- BN stats into slot (t0+tl, layer), slice layout ----------------
__global__ __launch_bounds__(256) void k_bnstats(const ushort* x, float* slots, int t0, int layer){
  const int tl = blockIdx.y;
  float* slot = slots + ((size_t)(t0+tl)*2 + layer)*2*HH;
  int h = threadIdx.x & 127;
  int g = threadIdx.x >> 7;
  int slice = tl*2 + (h>>6);
  const ushort* base = x + (long)slice*SLICE_E + (h&63);
  float s = 0.f, ss = 0.f;
  for (int r = blockIdx.x*2 + g; r < NN; r += gridDim.x*2){
    float v = bu2f(base[(long)r*64]);
    s += v; ss += v*v;
  }
  __shared__ float sh[2][HH], shq[2][HH];
  sh[g][h] = s; shq[g][h] = ss;
  __syncthreads();
  if (g == 0){
    atomicAdd(&slot[h],    sh[0][h] + sh[1][h]);
    atomicAdd(&slot[HH+h], shq[0][h] + shq[1][h]);
  }
}

// ---------------- output head (bf16 h input) ----------------
__global__ void k_out(const ushort* h, const float* Wo, const float* bo, void* out, int n,
                      const int* flag){
  __shared__ float Ws[HH][CC+1];
  __shared__ float bs[CC];
  int tid = threadIdx.x;
  for (int i = tid; i < HH*CC; i += 256) Ws[i/CC][i%CC] = Wo[i];
  if (tid < CC) bs[tid] = bo[tid];
  __syncthreads();
  int row = blockIdx.x*16 + (tid >> 4);
  int c   = tid & 15;
  if (row >= n) return;
  const ushort* hr = h + (size_t)row*HH;
  float s = bs[c];
  #pragma unroll 8
  for (int j = 0; j < HH; j++) s += bu2f(hr[j])*Ws[j][c];
  float m = s;
  for (int o = 8; o; o >>= 1) m = fmaxf(m, __shfl_xor(m, o, 16));
  float e = expf(s - m);
  float sum = e;
  for (int o = 8; o; o >>= 1) sum += __shfl_xor(sum, o, 16);
  float v = s - m - logf(sum);
  size_t idx = (size_t)row*CC + c;
  if (*flag) ((bf16*)out)[idx] = __float2bfloat16(v);
  else       ((float*)out)[idx] = v;
}

// ---------------- launcher ----------------
static inline size_t alignup(size_t x){ return (x + 255) & ~(size_t)255; }
static inline int ceil_div(int a, int b){ return (a + b - 1)/b; }

extern "C" void kernel_launch(void* const* d_in, const int* in_sizes, int n_in,
                              void* d_out, int out_size, void* d_ws, size_t ws_size,
                              hipStream_t stream){
  const void* x_seq = d_in[0];
  const int*  eidx  = (const int*)d_in[1];
  const void* ew    = d_in[2];
  const void* W_in  = d_in[3];
  const void* b_in  = d_in[4];
  const void* W1    = d_in[5];
  // d_in[6] = bc1 : cancels under training-mode BN
  const void* g1    = d_in[7];
  const void* be1   = d_in[8];
  const void* W2    = d_in[9];
  // d_in[10] = bc2 : cancels under BN
  const void* g2    = d_in[11];
  const void* be2   = d_in[12];
  const void* Wih0  = d_in[13];
  const void* Whh0  = d_in[14];
  const void* bih0  = d_in[15];
  const void* bhh0  = d_in[16];
  const void* Wih1  = d_in[17];
  const void* Whh1  = d_in[18];
  const void* bih1  = d_in[19];
  const void* bhh1  = d_in[20];
  const void* W_out = d_in[21];
  const void* b_out = d_in[22];
  const int* src = eidx;
  const int* dst = eidx + EE;

  // workspace (~90 MB)
  char* p = (char*)d_ws;
  auto alloc = [&](size_t bytes)->void*{ void* r = (void*)p; p += alignup(bytes); return r; };
  int*   flag     = (int*)  alloc(4);
  ull*   deg64    = (ull*)  alloc((size_t)NN*8);
  float* dinv     = (float*)alloc(NN*4);
  float* selfn    = (float*)alloc(NN*4);
  int*   cnt      = (int*)  alloc(NN*4);
  int*   cursor   = (int*)  alloc(NN*4);
  int*   offs     = (int*)  alloc((NN+1)*4);
  int*   csr_src  = (int*)  alloc((size_t)EE*4);
  float* csr_norm = (float*)alloc((size_t)EE*4);
  ushort* B1sw  = (ushort*)alloc((size_t)P0*2);
  ushort* B2sw  = (ushort*)alloc((size_t)P1*2);
  ushort* B3sw  = (ushort*)alloc((size_t)P2*2);
  ushort* BG0sw = (ushort*)alloc((size_t)P3*2);
  ushort* BG1sw = (ushort*)alloc((size_t)P4*2);
  float* bias4_0 = (float*)alloc(4*HH*4);
  float* bias4_1 = (float*)alloc(4*HH*4);
  float* b_inF   = (float*)alloc(HH*4);
  float* W_outF  = (float*)alloc(HH*CC*4);
  float* b_outF  = (float*)alloc(CC*4);
  float* slots   = (float*)alloc((size_t)T_STEPS*2*2*HH*4);
  ushort* temp2b = (ushort*)alloc((size_t)8*SLICE_E*2);
  ushort* agg1b  = (ushort*)alloc((size_t)8*SLICE_E*2);
  ushort* agg2b  = (ushort*)alloc((size_t)8*SLICE_E*2);
  ushort* h0bufA = (ushort*)alloc((size_t)M_PAD*HH*2);
  ushort* h0bufB = (ushort*)alloc((size_t)M_PAD*HH*2);
  ushort* h1bufA = (ushort*)alloc((size_t)M_PAD*HH*2);
  ushort* h1bufB = (ushort*)alloc((size_t)M_PAD*HH*2);
  (void)ws_size; (void)n_in; (void)in_sizes; (void)out_size;

  const int TPB = 256;
  // ---- init (+probe in block 0), graph setup ----
  k_init2<<<ceil_div(NN,TPB), TPB, 0, stream>>>(x_seq, flag, deg64, cursor, NN);
  k_prep<<<ceil_div(PREP_TOT,TPB), TPB, 0, stream>>>(
      W_in, W1, W2, Wih0, Whh0, Wih1, Whh1, bih0, bhh0, bih1, bhh1,
      b_in, W_out, b_out,
      B1sw, B2sw, B3sw, BG0sw, BG1sw,
      bias4_0, bias4_1, b_inF, W_outF, b_outF,
      (float*)h0bufA, (float*)h1bufA, slots, flag);
  k_deg <<<ceil_div(EE,TPB), TPB, 0, stream>>>(dst, ew, deg64, EE, flag);
  k_dinv<<<ceil_div(NN,TPB), TPB, 0, stream>>>(deg64, dinv, selfn, cnt, NN);
  k_scan<<<1, 256, 0, stream>>>(cnt, offs, NN);
  k_fill<<<ceil_div(EE,TPB), TPB, 0, stream>>>(src, dst, ew, dinv, offs, cursor, csr_src, csr_norm, EE, flag);

  ushort* H0[2] = {h0bufA, h0bufB};
  ushort* H1[2] = {h1bufA, h1bufB};
  int cur = 0;

  // ---- main loop: 4 chunks of 4 timesteps ----
  for (int c = 0; c < NCHUNK; c++){
    int t0 = c*T_CHUNK;
    dim3 gg(NB32, T_CHUNK);
    dim3 gb(128, T_CHUNK);
    k_gcn01 <<<gg, 256, 0, stream>>>(x_seq, t0, flag, b_inF, (const short8*)B1sw, (const short8*)B2sw, temp2b);
    k_conv  <<<NBC*4, 256, 0, stream>>>(temp2b, agg1b, offs, csr_src, csr_norm, selfn);
    k_bnstats<<<gb, 256, 0, stream>>>(agg1b, slots, t0, 0);
    k_mgemm2b<<<gg, 256, 0, stream>>>(agg1b, slots, t0, g1, be1, flag, (const short8*)B3sw, temp2b);
    k_conv  <<<NBC*4, 256, 0, stream>>>(temp2b, agg2b, offs, csr_src, csr_norm, selfn);
    k_bnstats<<<gb, 256, 0, stream>>>(agg2b, slots, t0, 1);
    for (int tt = 0; tt < T_CHUNK; tt++){
      int t = t0 + tt;
      int nxt = cur ^ 1;
      k_gru2<<<NB32, 512, 0, stream>>>(agg2b, tt, slots, t,
                                       g2, be2, flag, H0[cur], H1[cur],
                                       (const short8*)BG0sw, (const short8*)BG1sw,
                                       bias4_0, bias4_1, H0[nxt], H1[nxt]);
      cur = nxt;
    }
  }

  // ---- output head ----
  k_out<<<ceil_div(NN,16), 256, 0, stream>>>(H1[cur], W_outF, b_outF, d_out, NN, flag);
}